// Round 5
// baseline (276.487 us; speedup 1.0000x reference)
//
#include <hip/hip_runtime.h>

#define HEADS 16
#define HD 64
#define DM 1024
#define LSEQ 4096
#define NEGF (-1.0e30f)

typedef __attribute__((ext_vector_type(8))) short bf16x8;
typedef __attribute__((ext_vector_type(4))) float f32x4;
typedef unsigned short u16;

#define MFMA16(a, b, c) __builtin_amdgcn_mfma_f32_16x16x32_bf16((a), (b), (c), 0, 0, 0)

static __device__ __forceinline__ float b2f(u16 u) {
  union { float f; unsigned i; } t; t.i = ((unsigned)u) << 16; return t.f;
}
static __device__ __forceinline__ u16 f2b(float f) {
  union { float f; unsigned i; } t; t.f = f;
  unsigned r = t.i + 0x7fffu + ((t.i >> 16) & 1u);
  return (u16)(r >> 16);
}
static __device__ __forceinline__ ushort4 pk4(float4 v) {
  return make_ushort4(f2b(v.x), f2b(v.y), f2b(v.z), f2b(v.w));
}
static __device__ __forceinline__ void gload16(const void* g, void* l) {
  __builtin_amdgcn_global_load_lds((const __attribute__((address_space(1))) void*)g,
                                   (__attribute__((address_space(3))) void*)l, 16, 0, 0);
}

// ---------------- rope tables: cos/sin for window positions 0..511, dims 0..63 ----
__global__ void rope_build(float* __restrict__ ropc, float* __restrict__ rops) {
  int p = blockIdx.x, d = threadIdx.x;
  int t2 = d & ~1;
  double inv = pow(10000.0, -(double)t2 / 64.0);
  double f = (double)p * inv;
  ropc[p * 64 + d] = (float)cos(f);
  rops[p * 64 + d] = (float)sin(f);
}

// ---------------- weights f32 -> bf16 (4 at once) ----------------
__global__ void cvtw(const float4* __restrict__ a, const float4* __restrict__ b,
                     const float4* __restrict__ c, const float4* __restrict__ d,
                     ushort4* __restrict__ out) {
  int i = blockIdx.x * blockDim.x + threadIdx.x;  // 0..262143 (float4 units of 1M elems)
  out[i]          = pk4(a[i]);
  out[i + 262144] = pk4(b[i]);
  out[i + 524288] = pk4(c[i]);
  out[i + 786432] = pk4(d[i]);
}

// ---------------- LayerNorm rows (1024 wide) -> bf16 ----------------
__global__ __launch_bounds__(256) void ln_rows(const void* __restrict__ xin, int xbf,
                                               const float* __restrict__ gam,
                                               const float* __restrict__ bet,
                                               u16* __restrict__ out) {
  int row = blockIdx.x, tid = threadIdx.x;
  float4 v;
  if (xbf) {
    ushort4 u = ((const ushort4*)xin)[(size_t)row * 256 + tid];
    v.x = b2f(u.x); v.y = b2f(u.y); v.z = b2f(u.z); v.w = b2f(u.w);
  } else {
    v = ((const float4*)xin)[(size_t)row * 256 + tid];
  }
  float s = v.x + v.y + v.z + v.w;
  float s2 = v.x * v.x + v.y * v.y + v.z * v.z + v.w * v.w;
#pragma unroll
  for (int d = 1; d < 64; d <<= 1) { s += __shfl_xor(s, d); s2 += __shfl_xor(s2, d); }
  __shared__ float ps[8];
  int lane = tid & 63, wave = tid >> 6;
  if (lane == 0) { ps[wave] = s; ps[4 + wave] = s2; }
  __syncthreads();
  float tot = ps[0] + ps[1] + ps[2] + ps[3];
  float tot2 = ps[4] + ps[5] + ps[6] + ps[7];
  float mean = tot * (1.f / 1024.f);
  float var = tot2 * (1.f / 1024.f) - mean * mean;
  float rstd = rsqrtf(var + 1e-5f);
  float4 gv = ((const float4*)gam)[tid];
  float4 bv = ((const float4*)bet)[tid];
  ushort4 o = make_ushort4(f2b((v.x - mean) * rstd * gv.x + bv.x),
                           f2b((v.y - mean) * rstd * gv.y + bv.y),
                           f2b((v.z - mean) * rstd * gv.z + bv.z),
                           f2b((v.w - mean) * rstd * gv.w + bv.w));
  ((ushort4*)out)[(size_t)row * 256 + tid] = o;
}

// ---------------- NT GEMM: C[m][n] = sum_k A[m][k]*Bw[n][k] + bias[n] --------------
// 2-phase double-buffered: stage tile t+1 while computing tile t; ONE barrier/K-step
// (its implicit vmcnt(0) drain is the handshake for the prefetched buffer).
// modes: 0 = Q (rotary pos=l%256 -> bf16 BHLd)
//        1 = K (rotary pos=256+l%256 -> out0; pos=l%256 -> out1; bf16 BHLd)
//        2 = V (bf16 transposed BHdL)
//        3 = O (f32 row-major M x N)
__global__ __launch_bounds__(256, 2) void gemm_nt(
    const u16* __restrict__ A, const u16* __restrict__ Bw, const float* __restrict__ bias,
    const float* __restrict__ ropc, const float* __restrict__ rops,
    u16* __restrict__ out0, u16* __restrict__ out1, float* __restrict__ outf,
    int M, int N, int K, int mode) {
  __shared__ __align__(16) u16 Als[2][128 * 64];
  __shared__ __align__(16) u16 Bls[2][128 * 64];
  const int tid = threadIdx.x, lane = tid & 63, wave = tid >> 6;
  const int g = lane >> 4, ln15 = lane & 15;
  const int row0 = blockIdx.x * 128, col0 = blockIdx.y * 128;
  const int wm = (wave >> 1) * 64, wn = (wave & 1) * 64;
  f32x4 acc[4][4] = {};

#define STAGE(bi, k0s)                                                          \
  {                                                                             \
    _Pragma("unroll")                                                           \
    for (int i_ = 0; i_ < 4; ++i_) {                                            \
      int ch_ = i_ * 4 + wave;                                                  \
      int olin_ = ch_ * 1024 + lane * 16;                                       \
      int r_ = olin_ >> 7;                                                      \
      int cel_ = ((olin_ ^ ((r_ & 7) << 4)) >> 1) & 63;                         \
      gload16(A + (size_t)(row0 + r_) * K + (k0s) + cel_,                       \
              (char*)Als[bi] + ch_ * 1024);                                     \
    }                                                                           \
    _Pragma("unroll")                                                           \
    for (int i_ = 0; i_ < 4; ++i_) {                                            \
      int ch_ = i_ * 4 + wave;                                                  \
      int olin_ = ch_ * 1024 + lane * 16;                                       \
      int r_ = olin_ >> 7;                                                      \
      int cel_ = ((olin_ ^ ((r_ & 7) << 4)) >> 1) & 63;                         \
      gload16(Bw + (size_t)(col0 + r_) * K + (k0s) + cel_,                      \
              (char*)Bls[bi] + ch_ * 1024);                                     \
    }                                                                           \
  }

  STAGE(0, 0);
  __syncthreads();  // tile 0 staged (implicit vmcnt(0) drain)
  int cur = 0;
  for (int k0 = 0; k0 < K; k0 += 64) {
    if (k0 + 64 < K) STAGE(cur ^ 1, k0 + 64);  // prefetch next tile (in flight during compute)
#pragma unroll
    for (int ks = 0; ks < 2; ++ks) {
      bf16x8 af[4], bfv[4];
      int cb = (ks * 32 + g * 8) * 2;
#pragma unroll
      for (int mi = 0; mi < 4; ++mi) {
        int r = wm + mi * 16 + ln15;
        af[mi] = *(const bf16x8*)((const char*)Als[cur] + r * 128 + (cb ^ ((r & 7) << 4)));
      }
#pragma unroll
      for (int ni = 0; ni < 4; ++ni) {
        int r = wn + ni * 16 + ln15;
        bfv[ni] = *(const bf16x8*)((const char*)Bls[cur] + r * 128 + (cb ^ ((r & 7) << 4)));
      }
#pragma unroll
      for (int mi = 0; mi < 4; ++mi)
#pragma unroll
        for (int ni = 0; ni < 4; ++ni)
          acc[mi][ni] = MFMA16(af[mi], bfv[ni], acc[mi][ni]);
    }
    __syncthreads();  // drains prefetch (vmcnt 0) + all readers of buf[cur] done
    cur ^= 1;
  }
#undef STAGE

#pragma unroll
  for (int mi = 0; mi < 4; ++mi)
#pragma unroll
    for (int ni = 0; ni < 4; ++ni)
#pragma unroll
      for (int r = 0; r < 4; ++r) {
        int row = row0 + wm + mi * 16 + g * 4 + r;
        int col = col0 + wn + ni * 16 + ln15;
        float val = acc[mi][ni][r] + bias[col];
        if (mode == 3) {
          outf[(size_t)row * N + col] = val;
        } else if (mode == 2) {
          int bb = row >> 12, l = row & 4095, hh = col >> 6, d = col & 63;
          out0[(((size_t)bb * HEADS + hh) * HD + d) * LSEQ + l] = f2b(val);
        } else {
          float oth = __shfl_xor(val, 1);  // rotary partner (adjacent dim = adjacent lane)
          int bb = row >> 12, l = row & 4095, hh = col >> 6, d = col & 63;
          int pB = l & 255;
          size_t oidx = (((size_t)bb * HEADS + hh) * LSEQ + l) * HD + d;
          if (mode == 0) {
            float cc = ropc[pB * 64 + d], ss = rops[pB * 64 + d];
            out0[oidx] = f2b((d & 1) ? (val * cc + oth * ss) : (val * cc - oth * ss));
          } else {
            int pA = 256 + pB;
            float cA = ropc[pA * 64 + d], sA = rops[pA * 64 + d];
            out0[oidx] = f2b((d & 1) ? (val * cA + oth * sA) : (val * cA - oth * sA));
            float cB = ropc[pB * 64 + d], sB = rops[pB * 64 + d];
            out1[oidx] = f2b((d & 1) ? (val * cB + oth * sB) : (val * cB - oth * sB));
          }
        }
      }
}

// ---------------- fused windowed attention (v4: 8 waves x 32 q-rows, dbuf K) ------
// block = (b, h, bucket); 8 waves, each owns 32 q-rows; K staged 128 cols/stage,
// double-buffered (stage s+1 issued before computing s); 1 barrier per stage.
__global__ __launch_bounds__(512, 2) void attn_kernel(
    const u16* __restrict__ qrot,   // (B,H,L,64) rotated
    const u16* __restrict__ krotA,  // (B,H,L,64) rotated (current-bucket view)
    const u16* __restrict__ krotB,  // (B,H,L,64) rotated (prev-bucket view)
    const u16* __restrict__ vT,     // (B,H,64,L)
    const int* __restrict__ cell,   // (B,L)
    u16* __restrict__ o) {          // (B,L,1024) bf16
  __shared__ __align__(16) u16 Kc[2][128 * 64];  // dbuf K stages, swizzled, 2x16KB
  __shared__ __align__(16) u16 Pl[8 * 32 * 64];  // per-wave P relay, swizzled, 32KB
  __shared__ int ci[256];
  __shared__ int cj[512];

  const int tid = threadIdx.x, lane = tid & 63, wave = tid >> 6;
  const int g = lane >> 4, ln15 = lane & 15;
  const int bucket = blockIdx.x & 15;
  const int h = (blockIdx.x >> 4) & 15;
  const int b = blockIdx.x >> 8;
  const int w0 = bucket * 256;
  const size_t base = (size_t)(b * HEADS + h) * LSEQ * HD;

  if (tid < 256) ci[tid] = cell[b * LSEQ + w0 + tid];
  {
    int gj = w0 - 256 + tid;
    cj[tid] = (gj >= 0) ? cell[b * LSEQ + gj] : (int)0x80000000;
  }

  // Q fragments (already rotated): rows w0 + wave*32 + mi*16 + ln15
  bf16x8 qf[2][2];
#pragma unroll
  for (int mi = 0; mi < 2; ++mi)
#pragma unroll
    for (int ks = 0; ks < 2; ++ks)
      qf[mi][ks] = *(const bf16x8*)(qrot + base +
          (size_t)(w0 + wave * 32 + mi * 16 + ln15) * HD + ks * 32 + g * 8);

  f32x4 Oa[2][4] = {};
  float mrow[2][4], lrow[2][4];
#pragma unroll
  for (int a1 = 0; a1 < 2; ++a1)
#pragma unroll
    for (int a2 = 0; a2 < 4; ++a2) { mrow[a1][a2] = NEGF; lrow[a1][a2] = 0.f; }

#define STAGE_K(bi, s)                                                          \
  {                                                                             \
    const u16* ksrc_ = ((s) < 2) ? krotB : krotA;                               \
    int gj0_ = w0 - 256 + (s) * 128;                                            \
    _Pragma("unroll")                                                           \
    for (int i_ = 0; i_ < 2; ++i_) {                                            \
      int ch_ = i_ * 8 + wave;                                                  \
      int olin_ = ch_ * 1024 + lane * 16;                                       \
      int r_ = olin_ >> 7;                                                      \
      int cel_ = ((olin_ ^ ((r_ & 7) << 4)) >> 1) & 63;                         \
      gload16(ksrc_ + base + (size_t)(gj0_ + r_) * HD + cel_,                   \
              (char*)Kc[bi] + ch_ * 1024);                                      \
    }                                                                           \
  }

  const int s0 = (bucket == 0) ? 2 : 0;
  STAGE_K(0, s0);
  __syncthreads();  // stage s0 ready

  for (int s = s0; s < 4; ++s) {
    const int cur = (s - s0) & 1;
    if (s + 1 < 4) STAGE_K(cur ^ 1, s + 1);  // prefetch next stage into other buf

    // two 64-col sub-chunks within this stage
#pragma unroll
    for (int sub = 0; sub < 2; ++sub) {
      const int k = s * 2 + sub;                   // 64-col chunk index 0..7
      if (k * 64 > wave * 32 + 287) continue;      // causal: no col in chunk reachable
      const int gj0 = w0 - 256 + k * 64;           // global col base of chunk
      const int lr0 = sub * 64;                    // local row base in Kc stage

#pragma unroll
      for (int mi = 0; mi < 2; ++mi) {
        f32x4 sc[4] = {};
#pragma unroll
        for (int ks = 0; ks < 2; ++ks) {
          int cb = (ks * 32 + g * 8) * 2;
#pragma unroll
          for (int ni = 0; ni < 4; ++ni) {
            int r = lr0 + ni * 16 + ln15;
            bf16x8 kf = *(const bf16x8*)((const char*)Kc[cur] + r * 128 + (cb ^ ((r & 7) << 4)));
            sc[ni] = MFMA16(qf[mi][ks], kf, sc[ni]);
          }
        }
        // mask + scale + row max
        float mx[4] = {NEGF, NEGF, NEGF, NEGF};
#pragma unroll
        for (int ni = 0; ni < 4; ++ni)
#pragma unroll
          for (int r = 0; r < 4; ++r) {
            int iloc = wave * 32 + mi * 16 + g * 4 + r;
            int p = k * 64 + ni * 16 + ln15;
            bool ok = (p <= iloc + 256) && (ci[iloc] == cj[p]);
            float sv = ok ? sc[ni][r] * 0.125f : NEGF;
            sc[ni][r] = sv;
            mx[r] = fmaxf(mx[r], sv);
          }
#pragma unroll
        for (int d = 1; d < 16; d <<= 1)
#pragma unroll
          for (int r = 0; r < 4; ++r) mx[r] = fmaxf(mx[r], __shfl_xor(mx[r], d));
        float rs[4];
#pragma unroll
        for (int r = 0; r < 4; ++r) {
          float mold = mrow[mi][r];
          float mnew = fmaxf(mold, mx[r]);
          float alpha = __expf(mold - mnew);  // NEG,NEG -> 1 (l=0,O=0); NEG,finite -> 0
          mrow[mi][r] = mnew;
          lrow[mi][r] *= alpha;
#pragma unroll
          for (int nd = 0; nd < 4; ++nd) Oa[mi][nd][r] *= alpha;
          rs[r] = 0.f;
        }
#pragma unroll
        for (int ni = 0; ni < 4; ++ni)
#pragma unroll
          for (int r = 0; r < 4; ++r) {
            float sv = sc[ni][r];
            float p = (sv > NEGF * 0.5f) ? __expf(sv - mrow[mi][r]) : 0.f;
            u16 pb = f2b(p);
            rs[r] += b2f(pb);
            int row = mi * 16 + g * 4 + r;
            int colb = (ni * 16 + ln15) * 2;
            *(u16*)((char*)Pl + wave * 4096 + row * 128 + (colb ^ ((row & 7) << 4))) = pb;
          }
#pragma unroll
        for (int d = 1; d < 16; d <<= 1)
#pragma unroll
          for (int r = 0; r < 4; ++r) rs[r] += __shfl_xor(rs[r], d);
#pragma unroll
        for (int r = 0; r < 4; ++r) lrow[mi][r] += rs[r];
      }  // mi

      // PV: O += P(32x64) * V(64x64); V fragments direct from global
#pragma unroll
      for (int jb = 0; jb < 2; ++jb) {
        bf16x8 pa[2], vb[4];
        int cb = (jb * 32 + g * 8) * 2;
#pragma unroll
        for (int mi = 0; mi < 2; ++mi) {
          int row = mi * 16 + ln15;
          pa[mi] = *(const bf16x8*)((const char*)Pl + wave * 4096 + row * 128 + (cb ^ ((row & 7) << 4)));
        }
#pragma unroll
        for (int nd = 0; nd < 4; ++nd) {
          int d = nd * 16 + ln15;
          int p0 = gj0 + jb * 32 + g * 8;
          vb[nd] = *(const bf16x8*)(vT + base + (size_t)d * LSEQ + p0);
        }
#pragma unroll
        for (int mi = 0; mi < 2; ++mi)
#pragma unroll
          for (int nd = 0; nd < 4; ++nd) Oa[mi][nd] = MFMA16(pa[mi], vb[nd], Oa[mi][nd]);
      }
    }  // sub

    __syncthreads();  // stage s+1 writes complete + all readers of Kc[cur] done
  }  // stages

  // epilogue: normalize and store
#pragma unroll
  for (int mi = 0; mi < 2; ++mi)
#pragma unroll
    for (int r = 0; r < 4; ++r) {
      float invl = 1.0f / lrow[mi][r];
      int gi = w0 + wave * 32 + mi * 16 + g * 4 + r;
      size_t ob = ((size_t)b * LSEQ + gi) * DM + h * HD;
#pragma unroll
      for (int nd = 0; nd < 4; ++nd) o[ob + nd * 16 + ln15] = f2b(Oa[mi][nd][r] * invl);
    }
#undef STAGE_K
}

extern "C" void kernel_launch(void* const* d_in, const int* in_sizes, int n_in,
                              void* d_out, int out_size, void* d_ws, size_t ws_size,
                              hipStream_t stream) {
  const float* q = (const float*)d_in[0];
  const float* k = (const float*)d_in[1];
  const float* v = (const float*)d_in[2];
  const int* cell = (const int*)d_in[3];
  const float* lnw[4] = {(const float*)d_in[4], (const float*)d_in[8], (const float*)d_in[12], (const float*)d_in[16]};
  const float* lnb[4] = {(const float*)d_in[5], (const float*)d_in[9], (const float*)d_in[13], (const float*)d_in[17]};
  const float* Wm[4]  = {(const float*)d_in[6], (const float*)d_in[10], (const float*)d_in[14], (const float*)d_in[18]};
  const float* bi[4]  = {(const float*)d_in[7], (const float*)d_in[11], (const float*)d_in[15], (const float*)d_in[19]};

  char* ws = (char*)d_ws;
  u16* xln   = (u16*)(ws);               // 16 MiB: LN'd activations (reused)
  u16* wbf   = (u16*)(ws + 16777216);    // 8 MiB: 4 bf16 weights
  u16* qrot  = (u16*)(ws + 25165824);    // 16 MiB
  u16* krA   = (u16*)(ws + 41943040);    // 16 MiB
  u16* krB   = (u16*)(ws + 58720256);    // 16 MiB
  u16* vT    = (u16*)(ws + 75497472);    // 16 MiB
  u16* obuf  = (u16*)(ws + 92274688);    // 16 MiB
  float* ropc = (float*)(ws + 109051904);
  float* rops = (float*)(ws + 109182976);  // end ~104.3 MiB

  cvtw<<<1024, 256, 0, stream>>>((const float4*)Wm[0], (const float4*)Wm[1],
                                 (const float4*)Wm[2], (const float4*)Wm[3], (ushort4*)wbf);
  rope_build<<<512, 64, 0, stream>>>(ropc, rops);

  dim3 gg(64, 8);
  ln_rows<<<8192, 256, 0, stream>>>(q, 0, lnw[0], lnb[0], xln);
  gemm_nt<<<gg, 256, 0, stream>>>(xln, wbf, bi[0], ropc, rops, qrot, nullptr, nullptr, 8192, 1024, 1024, 0);
  ln_rows<<<8192, 256, 0, stream>>>(k, 0, lnw[1], lnb[1], xln);
  gemm_nt<<<gg, 256, 0, stream>>>(xln, wbf + 1048576, bi[1], ropc, rops, krA, krB, nullptr, 8192, 1024, 1024, 1);
  ln_rows<<<8192, 256, 0, stream>>>(v, 0, lnw[2], lnb[2], xln);
  gemm_nt<<<gg, 256, 0, stream>>>(xln, wbf + 2097152, bi[2], ropc, rops, vT, nullptr, nullptr, 8192, 1024, 1024, 2);
  attn_kernel<<<512, 512, 0, stream>>>(qrot, krA, krB, vT, cell, obuf);
  ln_rows<<<8192, 256, 0, stream>>>(obuf, 1, lnw[3], lnb[3], xln);
  gemm_nt<<<gg, 256, 0, stream>>>(xln, wbf + 3145728, bi[3], ropc, rops, nullptr, nullptr, (float*)d_out, 8192, 1024, 1024, 3);
}

// Round 6
// 273.131 us; speedup vs baseline: 1.0123x; 1.0123x over previous
//
#include <hip/hip_runtime.h>

#define HEADS 16
#define HD 64
#define DM 1024
#define LSEQ 4096
#define NEGF (-1.0e30f)

typedef __attribute__((ext_vector_type(8))) short bf16x8;
typedef __attribute__((ext_vector_type(4))) float f32x4;
typedef unsigned short u16;

#define MFMA16(a, b, c) __builtin_amdgcn_mfma_f32_16x16x32_bf16((a), (b), (c), 0, 0, 0)

static __device__ __forceinline__ float b2f(u16 u) {
  union { float f; unsigned i; } t; t.i = ((unsigned)u) << 16; return t.f;
}
static __device__ __forceinline__ u16 f2b(float f) {
  union { float f; unsigned i; } t; t.f = f;
  unsigned r = t.i + 0x7fffu + ((t.i >> 16) & 1u);
  return (u16)(r >> 16);
}
static __device__ __forceinline__ ushort4 pk4(float4 v) {
  return make_ushort4(f2b(v.x), f2b(v.y), f2b(v.z), f2b(v.w));
}
static __device__ __forceinline__ void gload16(const void* g, void* l) {
  __builtin_amdgcn_global_load_lds((const __attribute__((address_space(1))) void*)g,
                                   (__attribute__((address_space(3))) void*)l, 16, 0, 0);
}

// ---------------- rope tables: cos/sin for window positions 0..511, dims 0..63 ----
__global__ void rope_build(float* __restrict__ ropc, float* __restrict__ rops) {
  int p = blockIdx.x, d = threadIdx.x;
  int t2 = d & ~1;
  double inv = pow(10000.0, -(double)t2 / 64.0);
  double f = (double)p * inv;
  ropc[p * 64 + d] = (float)cos(f);
  rops[p * 64 + d] = (float)sin(f);
}

// ---------------- weights f32 -> bf16 (4 at once) ----------------
__global__ void cvtw(const float4* __restrict__ a, const float4* __restrict__ b,
                     const float4* __restrict__ c, const float4* __restrict__ d,
                     ushort4* __restrict__ out) {
  int i = blockIdx.x * blockDim.x + threadIdx.x;  // 0..262143 (float4 units of 1M elems)
  out[i]          = pk4(a[i]);
  out[i + 262144] = pk4(b[i]);
  out[i + 524288] = pk4(c[i]);
  out[i + 786432] = pk4(d[i]);
}

// ---------------- LayerNorm rows (1024 wide) -> bf16 ----------------
__global__ __launch_bounds__(256) void ln_rows(const void* __restrict__ xin, int xbf,
                                               const float* __restrict__ gam,
                                               const float* __restrict__ bet,
                                               u16* __restrict__ out) {
  int row = blockIdx.x, tid = threadIdx.x;
  float4 v;
  if (xbf) {
    ushort4 u = ((const ushort4*)xin)[(size_t)row * 256 + tid];
    v.x = b2f(u.x); v.y = b2f(u.y); v.z = b2f(u.z); v.w = b2f(u.w);
  } else {
    v = ((const float4*)xin)[(size_t)row * 256 + tid];
  }
  float s = v.x + v.y + v.z + v.w;
  float s2 = v.x * v.x + v.y * v.y + v.z * v.z + v.w * v.w;
#pragma unroll
  for (int d = 1; d < 64; d <<= 1) { s += __shfl_xor(s, d); s2 += __shfl_xor(s2, d); }
  __shared__ float ps[8];
  int lane = tid & 63, wave = tid >> 6;
  if (lane == 0) { ps[wave] = s; ps[4 + wave] = s2; }
  __syncthreads();
  float tot = ps[0] + ps[1] + ps[2] + ps[3];
  float tot2 = ps[4] + ps[5] + ps[6] + ps[7];
  float mean = tot * (1.f / 1024.f);
  float var = tot2 * (1.f / 1024.f) - mean * mean;
  float rstd = rsqrtf(var + 1e-5f);
  float4 gv = ((const float4*)gam)[tid];
  float4 bv = ((const float4*)bet)[tid];
  ushort4 o = make_ushort4(f2b((v.x - mean) * rstd * gv.x + bv.x),
                           f2b((v.y - mean) * rstd * gv.y + bv.y),
                           f2b((v.z - mean) * rstd * gv.z + bv.z),
                           f2b((v.w - mean) * rstd * gv.w + bv.w));
  ((ushort4*)out)[(size_t)row * 256 + tid] = o;
}

// ---------------- NT GEMM: C[m][n] = sum_k A[m][k]*Bw[n][k] + bias[n] --------------
// Single-buffered m97 structure; launch_bounds(256,3) caps VGPR ~170 -> 3 blocks/CU
// (implicit wave-level overlap is the pipeline, per m97/m114). Flat grid 512 with
// XCD-chunked swizzle: XCD c owns M-panels [c*8, c*8+8) x all 8 N-tiles, so the
// 2MB A-panel + 2MB weights fit that XCD's 4MB L2.
// modes: 0 = Q (rotary pos=l%256 -> bf16 BHLd)
//        1 = K (rotary pos=256+l%256 -> out0; pos=l%256 -> out1; bf16 BHLd)
//        2 = V (bf16 transposed BHdL)
//        3 = O (f32 row-major M x N)
__global__ __launch_bounds__(256, 3) void gemm_nt(
    const u16* __restrict__ A, const u16* __restrict__ Bw, const float* __restrict__ bias,
    const float* __restrict__ ropc, const float* __restrict__ rops,
    u16* __restrict__ out0, u16* __restrict__ out1, float* __restrict__ outf,
    int M, int N, int K, int mode) {
  __shared__ __align__(16) u16 Als[128 * 64];
  __shared__ __align__(16) u16 Bls[128 * 64];
  const int tid = threadIdx.x, lane = tid & 63, wave = tid >> 6;
  const int g = lane >> 4, ln15 = lane & 15;
  // XCD-chunked swizzle (bijective; 512 blocks, 64 M-tiles x 8 N-tiles)
  const int bid = blockIdx.x;
  const int xcd = bid & 7, idx = bid >> 3;
  const int row0 = (xcd * 8 + (idx >> 3)) * 128;
  const int col0 = (idx & 7) * 128;
  const int wm = (wave >> 1) * 64, wn = (wave & 1) * 64;
  f32x4 acc[4][4] = {};

  for (int k0 = 0; k0 < K; k0 += 64) {
#pragma unroll
    for (int i = 0; i < 4; ++i) {  // A tile: 16KB, swizzled via pre-swizzled source
      int ch = i * 4 + wave;
      int olin = ch * 1024 + lane * 16;
      int r = olin >> 7;
      int cel = ((olin ^ ((r & 7) << 4)) >> 1) & 63;
      gload16(A + (size_t)(row0 + r) * K + k0 + cel, (char*)Als + ch * 1024);
    }
#pragma unroll
    for (int i = 0; i < 4; ++i) {  // B tile
      int ch = i * 4 + wave;
      int olin = ch * 1024 + lane * 16;
      int r = olin >> 7;
      int cel = ((olin ^ ((r & 7) << 4)) >> 1) & 63;
      gload16(Bw + (size_t)(col0 + r) * K + k0 + cel, (char*)Bls + ch * 1024);
    }
    __syncthreads();
#pragma unroll
    for (int ks = 0; ks < 2; ++ks) {
      bf16x8 af[4], bfv[4];
      int cb = (ks * 32 + g * 8) * 2;
#pragma unroll
      for (int mi = 0; mi < 4; ++mi) {
        int r = wm + mi * 16 + ln15;
        af[mi] = *(const bf16x8*)((const char*)Als + r * 128 + (cb ^ ((r & 7) << 4)));
      }
#pragma unroll
      for (int ni = 0; ni < 4; ++ni) {
        int r = wn + ni * 16 + ln15;
        bfv[ni] = *(const bf16x8*)((const char*)Bls + r * 128 + (cb ^ ((r & 7) << 4)));
      }
#pragma unroll
      for (int mi = 0; mi < 4; ++mi)
#pragma unroll
        for (int ni = 0; ni < 4; ++ni)
          acc[mi][ni] = MFMA16(af[mi], bfv[ni], acc[mi][ni]);
    }
    __syncthreads();
  }

#pragma unroll
  for (int mi = 0; mi < 4; ++mi)
#pragma unroll
    for (int ni = 0; ni < 4; ++ni)
#pragma unroll
      for (int r = 0; r < 4; ++r) {
        int row = row0 + wm + mi * 16 + g * 4 + r;
        int col = col0 + wn + ni * 16 + ln15;
        float val = acc[mi][ni][r] + bias[col];
        if (mode == 3) {
          outf[(size_t)row * N + col] = val;
        } else if (mode == 2) {
          int bb = row >> 12, l = row & 4095, hh = col >> 6, d = col & 63;
          out0[(((size_t)bb * HEADS + hh) * HD + d) * LSEQ + l] = f2b(val);
        } else {
          float oth = __shfl_xor(val, 1);  // rotary partner (adjacent dim = adjacent lane)
          int bb = row >> 12, l = row & 4095, hh = col >> 6, d = col & 63;
          int pB = l & 255;
          size_t oidx = (((size_t)bb * HEADS + hh) * LSEQ + l) * HD + d;
          if (mode == 0) {
            float cc = ropc[pB * 64 + d], ss = rops[pB * 64 + d];
            out0[oidx] = f2b((d & 1) ? (val * cc + oth * ss) : (val * cc - oth * ss));
          } else {
            int pA = 256 + pB;
            float cA = ropc[pA * 64 + d], sA = rops[pA * 64 + d];
            out0[oidx] = f2b((d & 1) ? (val * cA + oth * sA) : (val * cA - oth * sA));
            float cB = ropc[pB * 64 + d], sB = rops[pB * 64 + d];
            out1[oidx] = f2b((d & 1) ? (val * cB + oth * sB) : (val * cB - oth * sB));
          }
        }
      }
}

// ---------------- fused windowed attention (v4 + T5 setprio) ----------------------
// block = (b, h, bucket); 8 waves, each owns 32 q-rows; K staged 128 cols/stage,
// double-buffered (stage s+1 issued before computing s); 1 barrier per stage.
__global__ __launch_bounds__(512, 2) void attn_kernel(
    const u16* __restrict__ qrot,   // (B,H,L,64) rotated
    const u16* __restrict__ krotA,  // (B,H,L,64) rotated (current-bucket view)
    const u16* __restrict__ krotB,  // (B,H,L,64) rotated (prev-bucket view)
    const u16* __restrict__ vT,     // (B,H,64,L)
    const int* __restrict__ cell,   // (B,L)
    u16* __restrict__ o) {          // (B,L,1024) bf16
  __shared__ __align__(16) u16 Kc[2][128 * 64];  // dbuf K stages, swizzled, 2x16KB
  __shared__ __align__(16) u16 Pl[8 * 32 * 64];  // per-wave P relay, swizzled, 32KB
  __shared__ int ci[256];
  __shared__ int cj[512];

  const int tid = threadIdx.x, lane = tid & 63, wave = tid >> 6;
  const int g = lane >> 4, ln15 = lane & 15;
  const int bucket = blockIdx.x & 15;
  const int h = (blockIdx.x >> 4) & 15;
  const int b = blockIdx.x >> 8;
  const int w0 = bucket * 256;
  const size_t base = (size_t)(b * HEADS + h) * LSEQ * HD;

  if (tid < 256) ci[tid] = cell[b * LSEQ + w0 + tid];
  {
    int gj = w0 - 256 + tid;
    cj[tid] = (gj >= 0) ? cell[b * LSEQ + gj] : (int)0x80000000;
  }

  // Q fragments (already rotated): rows w0 + wave*32 + mi*16 + ln15
  bf16x8 qf[2][2];
#pragma unroll
  for (int mi = 0; mi < 2; ++mi)
#pragma unroll
    for (int ks = 0; ks < 2; ++ks)
      qf[mi][ks] = *(const bf16x8*)(qrot + base +
          (size_t)(w0 + wave * 32 + mi * 16 + ln15) * HD + ks * 32 + g * 8);

  f32x4 Oa[2][4] = {};
  float mrow[2][4], lrow[2][4];
#pragma unroll
  for (int a1 = 0; a1 < 2; ++a1)
#pragma unroll
    for (int a2 = 0; a2 < 4; ++a2) { mrow[a1][a2] = NEGF; lrow[a1][a2] = 0.f; }

#define STAGE_K(bi, s)                                                          \
  {                                                                             \
    const u16* ksrc_ = ((s) < 2) ? krotB : krotA;                               \
    int gj0_ = w0 - 256 + (s) * 128;                                            \
    _Pragma("unroll")                                                           \
    for (int i_ = 0; i_ < 2; ++i_) {                                            \
      int ch_ = i_ * 8 + wave;                                                  \
      int olin_ = ch_ * 1024 + lane * 16;                                       \
      int r_ = olin_ >> 7;                                                      \
      int cel_ = ((olin_ ^ ((r_ & 7) << 4)) >> 1) & 63;                         \
      gload16(ksrc_ + base + (size_t)(gj0_ + r_) * HD + cel_,                   \
              (char*)Kc[bi] + ch_ * 1024);                                      \
    }                                                                           \
  }

  const int s0 = (bucket == 0) ? 2 : 0;
  STAGE_K(0, s0);
  __syncthreads();  // stage s0 ready

  for (int s = s0; s < 4; ++s) {
    const int cur = (s - s0) & 1;
    if (s + 1 < 4) STAGE_K(cur ^ 1, s + 1);  // prefetch next stage into other buf

    // two 64-col sub-chunks within this stage
#pragma unroll
    for (int sub = 0; sub < 2; ++sub) {
      const int k = s * 2 + sub;                   // 64-col chunk index 0..7
      if (k * 64 > wave * 32 + 287) continue;      // causal: no col in chunk reachable
      const int gj0 = w0 - 256 + k * 64;           // global col base of chunk
      const int lr0 = sub * 64;                    // local row base in Kc stage

#pragma unroll
      for (int mi = 0; mi < 2; ++mi) {
        f32x4 sc[4] = {};
        __builtin_amdgcn_s_setprio(1);
#pragma unroll
        for (int ks = 0; ks < 2; ++ks) {
          int cb = (ks * 32 + g * 8) * 2;
#pragma unroll
          for (int ni = 0; ni < 4; ++ni) {
            int r = lr0 + ni * 16 + ln15;
            bf16x8 kf = *(const bf16x8*)((const char*)Kc[cur] + r * 128 + (cb ^ ((r & 7) << 4)));
            sc[ni] = MFMA16(qf[mi][ks], kf, sc[ni]);
          }
        }
        __builtin_amdgcn_s_setprio(0);
        // mask + scale + row max
        float mx[4] = {NEGF, NEGF, NEGF, NEGF};
#pragma unroll
        for (int ni = 0; ni < 4; ++ni)
#pragma unroll
          for (int r = 0; r < 4; ++r) {
            int iloc = wave * 32 + mi * 16 + g * 4 + r;
            int p = k * 64 + ni * 16 + ln15;
            bool ok = (p <= iloc + 256) && (ci[iloc] == cj[p]);
            float sv = ok ? sc[ni][r] * 0.125f : NEGF;
            sc[ni][r] = sv;
            mx[r] = fmaxf(mx[r], sv);
          }
#pragma unroll
        for (int d = 1; d < 16; d <<= 1)
#pragma unroll
          for (int r = 0; r < 4; ++r) mx[r] = fmaxf(mx[r], __shfl_xor(mx[r], d));
        float rs[4];
#pragma unroll
        for (int r = 0; r < 4; ++r) {
          float mold = mrow[mi][r];
          float mnew = fmaxf(mold, mx[r]);
          float alpha = __expf(mold - mnew);  // NEG,NEG -> 1 (l=0,O=0); NEG,finite -> 0
          mrow[mi][r] = mnew;
          lrow[mi][r] *= alpha;
#pragma unroll
          for (int nd = 0; nd < 4; ++nd) Oa[mi][nd][r] *= alpha;
          rs[r] = 0.f;
        }
#pragma unroll
        for (int ni = 0; ni < 4; ++ni)
#pragma unroll
          for (int r = 0; r < 4; ++r) {
            float sv = sc[ni][r];
            float p = (sv > NEGF * 0.5f) ? __expf(sv - mrow[mi][r]) : 0.f;
            u16 pb = f2b(p);
            rs[r] += b2f(pb);
            int row = mi * 16 + g * 4 + r;
            int colb = (ni * 16 + ln15) * 2;
            *(u16*)((char*)Pl + wave * 4096 + row * 128 + (colb ^ ((row & 7) << 4))) = pb;
          }
#pragma unroll
        for (int d = 1; d < 16; d <<= 1)
#pragma unroll
          for (int r = 0; r < 4; ++r) rs[r] += __shfl_xor(rs[r], d);
#pragma unroll
        for (int r = 0; r < 4; ++r) lrow[mi][r] += rs[r];
      }  // mi

      // PV: O += P(32x64) * V(64x64); V fragments direct from global
#pragma unroll
      for (int jb = 0; jb < 2; ++jb) {
        bf16x8 pa[2], vb[4];
        int cb = (jb * 32 + g * 8) * 2;
#pragma unroll
        for (int mi = 0; mi < 2; ++mi) {
          int row = mi * 16 + ln15;
          pa[mi] = *(const bf16x8*)((const char*)Pl + wave * 4096 + row * 128 + (cb ^ ((row & 7) << 4)));
        }
#pragma unroll
        for (int nd = 0; nd < 4; ++nd) {
          int d = nd * 16 + ln15;
          int p0 = gj0 + jb * 32 + g * 8;
          vb[nd] = *(const bf16x8*)(vT + base + (size_t)d * LSEQ + p0);
        }
        __builtin_amdgcn_s_setprio(1);
#pragma unroll
        for (int mi = 0; mi < 2; ++mi)
#pragma unroll
          for (int nd = 0; nd < 4; ++nd) Oa[mi][nd] = MFMA16(pa[mi], vb[nd], Oa[mi][nd]);
        __builtin_amdgcn_s_setprio(0);
      }
    }  // sub

    __syncthreads();  // stage s+1 writes complete + all readers of Kc[cur] done
  }  // stages

  // epilogue: normalize and store
#pragma unroll
  for (int mi = 0; mi < 2; ++mi)
#pragma unroll
    for (int r = 0; r < 4; ++r) {
      float invl = 1.0f / lrow[mi][r];
      int gi = w0 + wave * 32 + mi * 16 + g * 4 + r;
      size_t ob = ((size_t)b * LSEQ + gi) * DM + h * HD;
#pragma unroll
      for (int nd = 0; nd < 4; ++nd) o[ob + nd * 16 + ln15] = f2b(Oa[mi][nd][r] * invl);
    }
#undef STAGE_K
}

extern "C" void kernel_launch(void* const* d_in, const int* in_sizes, int n_in,
                              void* d_out, int out_size, void* d_ws, size_t ws_size,
                              hipStream_t stream) {
  const float* q = (const float*)d_in[0];
  const float* k = (const float*)d_in[1];
  const float* v = (const float*)d_in[2];
  const int* cell = (const int*)d_in[3];
  const float* lnw[4] = {(const float*)d_in[4], (const float*)d_in[8], (const float*)d_in[12], (const float*)d_in[16]};
  const float* lnb[4] = {(const float*)d_in[5], (const float*)d_in[9], (const float*)d_in[13], (const float*)d_in[17]};
  const float* Wm[4]  = {(const float*)d_in[6], (const float*)d_in[10], (const float*)d_in[14], (const float*)d_in[18]};
  const float* bi[4]  = {(const float*)d_in[7], (const float*)d_in[11], (const float*)d_in[15], (const float*)d_in[19]};

  char* ws = (char*)d_ws;
  u16* xln   = (u16*)(ws);               // 16 MiB: LN'd activations (reused)
  u16* wbf   = (u16*)(ws + 16777216);    // 8 MiB: 4 bf16 weights
  u16* qrot  = (u16*)(ws + 25165824);    // 16 MiB
  u16* krA   = (u16*)(ws + 41943040);    // 16 MiB
  u16* krB   = (u16*)(ws + 58720256);    // 16 MiB
  u16* vT    = (u16*)(ws + 75497472);    // 16 MiB
  u16* obuf  = (u16*)(ws + 92274688);    // 16 MiB
  float* ropc = (float*)(ws + 109051904);
  float* rops = (float*)(ws + 109182976);  // end ~104.3 MiB

  cvtw<<<1024, 256, 0, stream>>>((const float4*)Wm[0], (const float4*)Wm[1],
                                 (const float4*)Wm[2], (const float4*)Wm[3], (ushort4*)wbf);
  rope_build<<<512, 64, 0, stream>>>(ropc, rops);

  ln_rows<<<8192, 256, 0, stream>>>(q, 0, lnw[0], lnb[0], xln);
  gemm_nt<<<512, 256, 0, stream>>>(xln, wbf, bi[0], ropc, rops, qrot, nullptr, nullptr, 8192, 1024, 1024, 0);
  ln_rows<<<8192, 256, 0, stream>>>(k, 0, lnw[1], lnb[1], xln);
  gemm_nt<<<512, 256, 0, stream>>>(xln, wbf + 1048576, bi[1], ropc, rops, krA, krB, nullptr, 8192, 1024, 1024, 1);
  ln_rows<<<8192, 256, 0, stream>>>(v, 0, lnw[2], lnb[2], xln);
  gemm_nt<<<512, 256, 0, stream>>>(xln, wbf + 2097152, bi[2], ropc, rops, vT, nullptr, nullptr, 8192, 1024, 1024, 2);
  attn_kernel<<<512, 512, 0, stream>>>(qrot, krA, krB, vT, cell, obuf);
  ln_rows<<<8192, 256, 0, stream>>>(obuf, 1, lnw[3], lnb[3], xln);
  gemm_nt<<<512, 256, 0, stream>>>(xln, wbf + 3145728, bi[3], ropc, rops, nullptr, nullptr, (float*)d_out, 8192, 1024, 1024, 3);
}

// Round 7
// 247.438 us; speedup vs baseline: 1.1174x; 1.1038x over previous
//
#include <hip/hip_runtime.h>

#define HEADS 16
#define HD 64
#define DM 1024
#define LSEQ 4096
#define NEGF (-1.0e30f)

typedef __attribute__((ext_vector_type(8))) short bf16x8;
typedef __attribute__((ext_vector_type(4))) float f32x4;
typedef unsigned short u16;

#define MFMA16(a, b, c) __builtin_amdgcn_mfma_f32_16x16x32_bf16((a), (b), (c), 0, 0, 0)

static __device__ __forceinline__ float b2f(u16 u) {
  union { float f; unsigned i; } t; t.i = ((unsigned)u) << 16; return t.f;
}
static __device__ __forceinline__ u16 f2b(float f) {
  union { float f; unsigned i; } t; t.f = f;
  unsigned r = t.i + 0x7fffu + ((t.i >> 16) & 1u);
  return (u16)(r >> 16);
}
static __device__ __forceinline__ ushort4 pk4(float4 v) {
  return make_ushort4(f2b(v.x), f2b(v.y), f2b(v.z), f2b(v.w));
}
static __device__ __forceinline__ void gload16(const void* g, void* l) {
  __builtin_amdgcn_global_load_lds((const __attribute__((address_space(1))) void*)g,
                                   (__attribute__((address_space(3))) void*)l, 16, 0, 0);
}

// ---------------- rope tables: cos/sin for window positions 0..511, dims 0..63 ----
__global__ void rope_build(float* __restrict__ ropc, float* __restrict__ rops) {
  int p = blockIdx.x, d = threadIdx.x;
  int t2 = d & ~1;
  double inv = pow(10000.0, -(double)t2 / 64.0);
  double f = (double)p * inv;
  ropc[p * 64 + d] = (float)cos(f);
  rops[p * 64 + d] = (float)sin(f);
}

// ---------------- weights f32 -> bf16 (4 at once) ----------------
__global__ void cvtw(const float4* __restrict__ a, const float4* __restrict__ b,
                     const float4* __restrict__ c, const float4* __restrict__ d,
                     ushort4* __restrict__ out) {
  int i = blockIdx.x * blockDim.x + threadIdx.x;  // 0..262143 (float4 units of 1M elems)
  out[i]          = pk4(a[i]);
  out[i + 262144] = pk4(b[i]);
  out[i + 524288] = pk4(c[i]);
  out[i + 786432] = pk4(d[i]);
}

// ---------------- LayerNorm rows (1024 wide) -> bf16 ----------------
__global__ __launch_bounds__(256) void ln_rows(const void* __restrict__ xin, int xbf,
                                               const float* __restrict__ gam,
                                               const float* __restrict__ bet,
                                               u16* __restrict__ out) {
  int row = blockIdx.x, tid = threadIdx.x;
  float4 v;
  if (xbf) {
    ushort4 u = ((const ushort4*)xin)[(size_t)row * 256 + tid];
    v.x = b2f(u.x); v.y = b2f(u.y); v.z = b2f(u.z); v.w = b2f(u.w);
  } else {
    v = ((const float4*)xin)[(size_t)row * 256 + tid];
  }
  float s = v.x + v.y + v.z + v.w;
  float s2 = v.x * v.x + v.y * v.y + v.z * v.z + v.w * v.w;
#pragma unroll
  for (int d = 1; d < 64; d <<= 1) { s += __shfl_xor(s, d); s2 += __shfl_xor(s2, d); }
  __shared__ float ps[8];
  int lane = tid & 63, wave = tid >> 6;
  if (lane == 0) { ps[wave] = s; ps[4 + wave] = s2; }
  __syncthreads();
  float tot = ps[0] + ps[1] + ps[2] + ps[3];
  float tot2 = ps[4] + ps[5] + ps[6] + ps[7];
  float mean = tot * (1.f / 1024.f);
  float var = tot2 * (1.f / 1024.f) - mean * mean;
  float rstd = rsqrtf(var + 1e-5f);
  float4 gv = ((const float4*)gam)[tid];
  float4 bv = ((const float4*)bet)[tid];
  ushort4 o = make_ushort4(f2b((v.x - mean) * rstd * gv.x + bv.x),
                           f2b((v.y - mean) * rstd * gv.y + bv.y),
                           f2b((v.z - mean) * rstd * gv.z + bv.z),
                           f2b((v.w - mean) * rstd * gv.w + bv.w));
  ((ushort4*)out)[(size_t)row * 256 + tid] = o;
}

// ---------------- NT GEMM: C[m][n] = sum_k A[m][k]*Bw[n][k] + bias[n] --------------
// Single-buffered m97 structure; XCD-chunked flat grid.
// modes: 0 = Q (scaled by 0.125, rotary pos=l%256 -> bf16 BHLd)
//        1 = K (rotary pos=256+l%256 -> out0; pos=l%256 -> out1; bf16 BHLd)
//        2 = V (bf16 transposed BHdL)
//        3 = O (f32 row-major M x N)
__global__ __launch_bounds__(256, 3) void gemm_nt(
    const u16* __restrict__ A, const u16* __restrict__ Bw, const float* __restrict__ bias,
    const float* __restrict__ ropc, const float* __restrict__ rops,
    u16* __restrict__ out0, u16* __restrict__ out1, float* __restrict__ outf,
    int M, int N, int K, int mode) {
  __shared__ __align__(16) u16 Als[128 * 64];
  __shared__ __align__(16) u16 Bls[128 * 64];
  const int tid = threadIdx.x, lane = tid & 63, wave = tid >> 6;
  const int g = lane >> 4, ln15 = lane & 15;
  // XCD-chunked swizzle (bijective; 512 blocks, 64 M-tiles x 8 N-tiles)
  const int bid = blockIdx.x;
  const int xcd = bid & 7, idx = bid >> 3;
  const int row0 = (xcd * 8 + (idx >> 3)) * 128;
  const int col0 = (idx & 7) * 128;
  const int wm = (wave >> 1) * 64, wn = (wave & 1) * 64;
  f32x4 acc[4][4] = {};

  for (int k0 = 0; k0 < K; k0 += 64) {
#pragma unroll
    for (int i = 0; i < 4; ++i) {  // A tile: 16KB, swizzled via pre-swizzled source
      int ch = i * 4 + wave;
      int olin = ch * 1024 + lane * 16;
      int r = olin >> 7;
      int cel = ((olin ^ ((r & 7) << 4)) >> 1) & 63;
      gload16(A + (size_t)(row0 + r) * K + k0 + cel, (char*)Als + ch * 1024);
    }
#pragma unroll
    for (int i = 0; i < 4; ++i) {  // B tile
      int ch = i * 4 + wave;
      int olin = ch * 1024 + lane * 16;
      int r = olin >> 7;
      int cel = ((olin ^ ((r & 7) << 4)) >> 1) & 63;
      gload16(Bw + (size_t)(col0 + r) * K + k0 + cel, (char*)Bls + ch * 1024);
    }
    __syncthreads();
#pragma unroll
    for (int ks = 0; ks < 2; ++ks) {
      bf16x8 af[4], bfv[4];
      int cb = (ks * 32 + g * 8) * 2;
#pragma unroll
      for (int mi = 0; mi < 4; ++mi) {
        int r = wm + mi * 16 + ln15;
        af[mi] = *(const bf16x8*)((const char*)Als + r * 128 + (cb ^ ((r & 7) << 4)));
      }
#pragma unroll
      for (int ni = 0; ni < 4; ++ni) {
        int r = wn + ni * 16 + ln15;
        bfv[ni] = *(const bf16x8*)((const char*)Bls + r * 128 + (cb ^ ((r & 7) << 4)));
      }
#pragma unroll
      for (int mi = 0; mi < 4; ++mi)
#pragma unroll
        for (int ni = 0; ni < 4; ++ni)
          acc[mi][ni] = MFMA16(af[mi], bfv[ni], acc[mi][ni]);
    }
    __syncthreads();
  }

#pragma unroll
  for (int mi = 0; mi < 4; ++mi)
#pragma unroll
    for (int ni = 0; ni < 4; ++ni)
#pragma unroll
      for (int r = 0; r < 4; ++r) {
        int row = row0 + wm + mi * 16 + g * 4 + r;
        int col = col0 + wn + ni * 16 + ln15;
        float val = acc[mi][ni][r] + bias[col];
        if (mode == 3) {
          outf[(size_t)row * N + col] = val;
        } else if (mode == 2) {
          int bb = row >> 12, l = row & 4095, hh = col >> 6, d = col & 63;
          out0[(((size_t)bb * HEADS + hh) * HD + d) * LSEQ + l] = f2b(val);
        } else {
          if (mode == 0) val *= 0.125f;      // fold 1/sqrt(hd) into Q
          float oth = __shfl_xor(val, 1);    // rotary partner (adjacent dim = adjacent lane)
          int bb = row >> 12, l = row & 4095, hh = col >> 6, d = col & 63;
          int pB = l & 255;
          size_t oidx = (((size_t)bb * HEADS + hh) * LSEQ + l) * HD + d;
          if (mode == 0) {
            float cc = ropc[pB * 64 + d], ss = rops[pB * 64 + d];
            out0[oidx] = f2b((d & 1) ? (val * cc + oth * ss) : (val * cc - oth * ss));
          } else {
            int pA = 256 + pB;
            float cA = ropc[pA * 64 + d], sA = rops[pA * 64 + d];
            out0[oidx] = f2b((d & 1) ? (val * cA + oth * sA) : (val * cA - oth * sA));
            float cB = ropc[pB * 64 + d], sB = rops[pB * 64 + d];
            out1[oidx] = f2b((d & 1) ? (val * cB + oth * sB) : (val * cB - oth * sB));
          }
        }
      }
}

// ---------------- fused windowed attention (v5: cell-interval chunk skip) ---------
// block = (b, h, bucket); 8 waves x 32 q-rows; K staged 128 cols/stage, dbuf.
// cell is SORTED per batch -> equality regions are intervals; disjoint cell ranges
// between a wave's rows and a chunk's cols => chunk fully masked => skip (exact).
__global__ __launch_bounds__(512, 2) void attn_kernel(
    const u16* __restrict__ qrot,   // (B,H,L,64) rotated, pre-scaled by 0.125
    const u16* __restrict__ krotA,  // (B,H,L,64) rotated (current-bucket view)
    const u16* __restrict__ krotB,  // (B,H,L,64) rotated (prev-bucket view)
    const u16* __restrict__ vT,     // (B,H,64,L)
    const int* __restrict__ cell,   // (B,L)
    u16* __restrict__ o) {          // (B,L,1024) bf16
  __shared__ __align__(16) u16 Kc[2][128 * 64];  // dbuf K stages, swizzled, 2x16KB
  __shared__ __align__(16) u16 Pl[8 * 32 * 64];  // per-wave P relay, swizzled, 32KB
  __shared__ int ci[256];
  __shared__ int cj[512];

  const int tid = threadIdx.x, lane = tid & 63, wave = tid >> 6;
  const int g = lane >> 4, ln15 = lane & 15;
  const int bucket = blockIdx.x & 15;
  const int h = (blockIdx.x >> 4) & 15;
  const int b = blockIdx.x >> 8;
  const int w0 = bucket * 256;
  const size_t base = (size_t)(b * HEADS + h) * LSEQ * HD;

  if (tid < 256) ci[tid] = cell[b * LSEQ + w0 + tid];
  {
    int gj = w0 - 256 + tid;
    cj[tid] = (gj >= 0) ? cell[b * LSEQ + gj] : (int)0x80000000;
  }

  // Q fragments (already rotated + scaled): rows w0 + wave*32 + mi*16 + ln15
  bf16x8 qf[2][2];
#pragma unroll
  for (int mi = 0; mi < 2; ++mi)
#pragma unroll
    for (int ks = 0; ks < 2; ++ks)
      qf[mi][ks] = *(const bf16x8*)(qrot + base +
          (size_t)(w0 + wave * 32 + mi * 16 + ln15) * HD + ks * 32 + g * 8);

  f32x4 Oa[2][4] = {};
  float mrow[2][4], lrow[2][4];
#pragma unroll
  for (int a1 = 0; a1 < 2; ++a1)
#pragma unroll
    for (int a2 = 0; a2 < 4; ++a2) { mrow[a1][a2] = NEGF; lrow[a1][a2] = 0.f; }

#define STAGE_K(bi, s)                                                          \
  {                                                                             \
    const u16* ksrc_ = ((s) < 2) ? krotB : krotA;                               \
    int gj0_ = w0 - 256 + (s) * 128;                                            \
    _Pragma("unroll")                                                           \
    for (int i_ = 0; i_ < 2; ++i_) {                                            \
      int ch_ = i_ * 8 + wave;                                                  \
      int olin_ = ch_ * 1024 + lane * 16;                                       \
      int r_ = olin_ >> 7;                                                      \
      int cel_ = ((olin_ ^ ((r_ & 7) << 4)) >> 1) & 63;                         \
      gload16(ksrc_ + base + (size_t)(gj0_ + r_) * HD + cel_,                   \
              (char*)Kc[bi] + ch_ * 1024);                                      \
    }                                                                           \
  }

  const int s0 = (bucket == 0) ? 2 : 0;
  STAGE_K(0, s0);
  __syncthreads();  // stage s0 ready; ci/cj visible

  // cell intervals (sorted): block rows, this wave's rows
  const int crb_lo = ci[0], crb_hi = ci[255];
  const int crw_lo = ci[wave * 32], crw_hi = ci[wave * 32 + 31];

  for (int s = s0; s < 4; ++s) {
    const int cur = (s - s0) & 1;
    if (s + 1 < 4) {
      // block-level staging skip: stage needed iff any of its 2 chunks' cell range
      // intersects the block's row range (block skip => every wave skips it)
      int k1 = (s + 1) * 2;
      bool need = false;
#pragma unroll
      for (int kk = 0; kk < 2; ++kk) {
        int clo = cj[(k1 + kk) * 64], chi = cj[(k1 + kk) * 64 + 63];
        need = need || !(chi < crb_lo || clo > crb_hi);
      }
      if (need) STAGE_K(cur ^ 1, s + 1);
    }

    // two 64-col sub-chunks within this stage
#pragma unroll
    for (int sub = 0; sub < 2; ++sub) {
      const int k = s * 2 + sub;                   // 64-col chunk index 0..7
      if (k * 64 > wave * 32 + 287) continue;      // causal: no col in chunk reachable
      {                                            // cell-interval skip (exact)
        int clo = cj[k * 64], chi = cj[k * 64 + 63];
        if (chi < crw_lo || clo > crw_hi) continue;
      }
      const int gj0 = w0 - 256 + k * 64;           // global col base of chunk
      const int lr0 = sub * 64;                    // local row base in Kc stage

#pragma unroll
      for (int mi = 0; mi < 2; ++mi) {
        f32x4 sc[4] = {};
        __builtin_amdgcn_s_setprio(1);
#pragma unroll
        for (int ks = 0; ks < 2; ++ks) {
          int cb = (ks * 32 + g * 8) * 2;
#pragma unroll
          for (int ni = 0; ni < 4; ++ni) {
            int r = lr0 + ni * 16 + ln15;
            bf16x8 kf = *(const bf16x8*)((const char*)Kc[cur] + r * 128 + (cb ^ ((r & 7) << 4)));
            sc[ni] = MFMA16(qf[mi][ks], kf, sc[ni]);
          }
        }
        __builtin_amdgcn_s_setprio(0);
        // mask + row max (scores pre-scaled via Q)
        float mx[4] = {NEGF, NEGF, NEGF, NEGF};
#pragma unroll
        for (int ni = 0; ni < 4; ++ni)
#pragma unroll
          for (int r = 0; r < 4; ++r) {
            int iloc = wave * 32 + mi * 16 + g * 4 + r;
            int p = k * 64 + ni * 16 + ln15;
            bool ok = (p <= iloc + 256) && (ci[iloc] == cj[p]);
            float sv = ok ? sc[ni][r] : NEGF;
            sc[ni][r] = sv;
            mx[r] = fmaxf(mx[r], sv);
          }
#pragma unroll
        for (int d = 1; d < 16; d <<= 1)
#pragma unroll
          for (int r = 0; r < 4; ++r) mx[r] = fmaxf(mx[r], __shfl_xor(mx[r], d));
        float rs[4] = {0.f, 0.f, 0.f, 0.f};
        // T13 defer-max: rescale only if max grew by > 8
        bool big = false;
#pragma unroll
        for (int r = 0; r < 4; ++r) big = big || (mx[r] > mrow[mi][r] + 8.0f);
        if (__any(big)) {
#pragma unroll
          for (int r = 0; r < 4; ++r) {
            float mold = mrow[mi][r];
            float mnew = fmaxf(mold, mx[r]);
            float alpha = __expf(mold - mnew);  // NEG,NEG -> 1; NEG,finite -> 0
            mrow[mi][r] = mnew;
            lrow[mi][r] *= alpha;
#pragma unroll
            for (int nd = 0; nd < 4; ++nd) Oa[mi][nd][r] *= alpha;
          }
        }
#pragma unroll
        for (int ni = 0; ni < 4; ++ni)
#pragma unroll
          for (int r = 0; r < 4; ++r) {
            float sv = sc[ni][r];
            float p = (sv > NEGF * 0.5f) ? __expf(sv - mrow[mi][r]) : 0.f;
            rs[r] += p;
            int row = mi * 16 + g * 4 + r;
            int colb = (ni * 16 + ln15) * 2;
            *(u16*)((char*)Pl + wave * 4096 + row * 128 + (colb ^ ((row & 7) << 4))) = f2b(p);
          }
#pragma unroll
        for (int d = 1; d < 16; d <<= 1)
#pragma unroll
          for (int r = 0; r < 4; ++r) rs[r] += __shfl_xor(rs[r], d);
#pragma unroll
        for (int r = 0; r < 4; ++r) lrow[mi][r] += rs[r];
      }  // mi

      // PV: O += P(32x64) * V(64x64); V fragments direct from global
#pragma unroll
      for (int jb = 0; jb < 2; ++jb) {
        bf16x8 pa[2], vb[4];
        int cb = (jb * 32 + g * 8) * 2;
#pragma unroll
        for (int mi = 0; mi < 2; ++mi) {
          int row = mi * 16 + ln15;
          pa[mi] = *(const bf16x8*)((const char*)Pl + wave * 4096 + row * 128 + (cb ^ ((row & 7) << 4)));
        }
#pragma unroll
        for (int nd = 0; nd < 4; ++nd) {
          int d = nd * 16 + ln15;
          int p0 = gj0 + jb * 32 + g * 8;
          vb[nd] = *(const bf16x8*)(vT + base + (size_t)d * LSEQ + p0);
        }
        __builtin_amdgcn_s_setprio(1);
#pragma unroll
        for (int mi = 0; mi < 2; ++mi)
#pragma unroll
          for (int nd = 0; nd < 4; ++nd) Oa[mi][nd] = MFMA16(pa[mi], vb[nd], Oa[mi][nd]);
        __builtin_amdgcn_s_setprio(0);
      }
    }  // sub

    __syncthreads();  // stage s+1 writes complete + all readers of Kc[cur] done
  }  // stages

  // epilogue: normalize and store
#pragma unroll
  for (int mi = 0; mi < 2; ++mi)
#pragma unroll
    for (int r = 0; r < 4; ++r) {
      float invl = 1.0f / lrow[mi][r];
      int gi = w0 + wave * 32 + mi * 16 + g * 4 + r;
      size_t ob = ((size_t)b * LSEQ + gi) * DM + h * HD;
#pragma unroll
      for (int nd = 0; nd < 4; ++nd) o[ob + nd * 16 + ln15] = f2b(Oa[mi][nd][r] * invl);
    }
#undef STAGE_K
}

extern "C" void kernel_launch(void* const* d_in, const int* in_sizes, int n_in,
                              void* d_out, int out_size, void* d_ws, size_t ws_size,
                              hipStream_t stream) {
  const float* q = (const float*)d_in[0];
  const float* k = (const float*)d_in[1];
  const float* v = (const float*)d_in[2];
  const int* cell = (const int*)d_in[3];
  const float* lnw[4] = {(const float*)d_in[4], (const float*)d_in[8], (const float*)d_in[12], (const float*)d_in[16]};
  const float* lnb[4] = {(const float*)d_in[5], (const float*)d_in[9], (const float*)d_in[13], (const float*)d_in[17]};
  const float* Wm[4]  = {(const float*)d_in[6], (const float*)d_in[10], (const float*)d_in[14], (const float*)d_in[18]};
  const float* bi[4]  = {(const float*)d_in[7], (const float*)d_in[11], (const float*)d_in[15], (const float*)d_in[19]};

  char* ws = (char*)d_ws;
  u16* xln   = (u16*)(ws);               // 16 MiB: LN'd activations (reused)
  u16* wbf   = (u16*)(ws + 16777216);    // 8 MiB: 4 bf16 weights
  u16* qrot  = (u16*)(ws + 25165824);    // 16 MiB
  u16* krA   = (u16*)(ws + 41943040);    // 16 MiB
  u16* krB   = (u16*)(ws + 58720256);    // 16 MiB
  u16* vT    = (u16*)(ws + 75497472);    // 16 MiB
  u16* obuf  = (u16*)(ws + 92274688);    // 16 MiB
  float* ropc = (float*)(ws + 109051904);
  float* rops = (float*)(ws + 109182976);  // end ~104.3 MiB

  cvtw<<<1024, 256, 0, stream>>>((const float4*)Wm[0], (const float4*)Wm[1],
                                 (const float4*)Wm[2], (const float4*)Wm[3], (ushort4*)wbf);
  rope_build<<<512, 64, 0, stream>>>(ropc, rops);

  ln_rows<<<8192, 256, 0, stream>>>(q, 0, lnw[0], lnb[0], xln);
  gemm_nt<<<512, 256, 0, stream>>>(xln, wbf, bi[0], ropc, rops, qrot, nullptr, nullptr, 8192, 1024, 1024, 0);
  ln_rows<<<8192, 256, 0, stream>>>(k, 0, lnw[1], lnb[1], xln);
  gemm_nt<<<512, 256, 0, stream>>>(xln, wbf + 1048576, bi[1], ropc, rops, krA, krB, nullptr, 8192, 1024, 1024, 1);
  ln_rows<<<8192, 256, 0, stream>>>(v, 0, lnw[2], lnb[2], xln);
  gemm_nt<<<512, 256, 0, stream>>>(xln, wbf + 2097152, bi[2], ropc, rops, vT, nullptr, nullptr, 8192, 1024, 1024, 2);
  attn_kernel<<<512, 512, 0, stream>>>(qrot, krA, krB, vT, cell, obuf);
  ln_rows<<<8192, 256, 0, stream>>>(obuf, 1, lnw[3], lnb[3], xln);
  gemm_nt<<<512, 256, 0, stream>>>(xln, wbf + 3145728, bi[3], ropc, rops, nullptr, nullptr, (float*)d_out, 8192, 1024, 1024, 3);
}

// Round 8
// 214.653 us; speedup vs baseline: 1.2881x; 1.1527x over previous
//
#include <hip/hip_runtime.h>

#define HEADS 16
#define HD 64
#define DM 1024
#define LSEQ 4096
#define NEGF (-1.0e30f)

typedef __attribute__((ext_vector_type(8))) short bf16x8;
typedef __attribute__((ext_vector_type(4))) float f32x4;
typedef unsigned short u16;

#define MFMA16(a, b, c) __builtin_amdgcn_mfma_f32_16x16x32_bf16((a), (b), (c), 0, 0, 0)

static __device__ __forceinline__ float b2f(u16 u) {
  union { float f; unsigned i; } t; t.i = ((unsigned)u) << 16; return t.f;
}
static __device__ __forceinline__ u16 f2b(float f) {
  union { float f; unsigned i; } t; t.f = f;
  unsigned r = t.i + 0x7fffu + ((t.i >> 16) & 1u);
  return (u16)(r >> 16);
}
static __device__ __forceinline__ ushort4 pk4(float4 v) {
  return make_ushort4(f2b(v.x), f2b(v.y), f2b(v.z), f2b(v.w));
}
static __device__ __forceinline__ void gload16(const void* g, void* l) {
  __builtin_amdgcn_global_load_lds((const __attribute__((address_space(1))) void*)g,
                                   (__attribute__((address_space(3))) void*)l, 16, 0, 0);
}

// ---------------- rope tables: cos/sin for window positions 0..511, dims 0..63 ----
__global__ void rope_build(float* __restrict__ ropc, float* __restrict__ rops) {
  int p = blockIdx.x, d = threadIdx.x;
  int t2 = d & ~1;
  double inv = pow(10000.0, -(double)t2 / 64.0);
  double f = (double)p * inv;
  ropc[p * 64 + d] = (float)cos(f);
  rops[p * 64 + d] = (float)sin(f);
}

// ---------------- weights f32 -> bf16 (4 at once) ----------------
__global__ void cvtw(const float4* __restrict__ a, const float4* __restrict__ b,
                     const float4* __restrict__ c, const float4* __restrict__ d,
                     ushort4* __restrict__ out) {
  int i = blockIdx.x * blockDim.x + threadIdx.x;  // 0..262143 (float4 units of 1M elems)
  out[i]          = pk4(a[i]);
  out[i + 262144] = pk4(b[i]);
  out[i + 524288] = pk4(c[i]);
  out[i + 786432] = pk4(d[i]);
}

// ---------------- fused LayerNorm for q,k,v (f32 in, bf16 out) --------------------
__global__ __launch_bounds__(256) void ln_qkv(
    const float4* __restrict__ q, const float4* __restrict__ k, const float4* __restrict__ v,
    const float* __restrict__ g0, const float* __restrict__ b0,
    const float* __restrict__ g1, const float* __restrict__ b1,
    const float* __restrict__ g2, const float* __restrict__ b2,
    ushort4* __restrict__ o0, ushort4* __restrict__ o1, ushort4* __restrict__ o2) {
  const int row = blockIdx.x, tid = threadIdx.x, sel = blockIdx.y;
  const float4* src = (sel == 0) ? q : (sel == 1) ? k : v;
  const float* gam = (sel == 0) ? g0 : (sel == 1) ? g1 : g2;
  const float* bet = (sel == 0) ? b0 : (sel == 1) ? b1 : b2;
  ushort4* dst = (sel == 0) ? o0 : (sel == 1) ? o1 : o2;

  float4 v4 = src[(size_t)row * 256 + tid];
  float s = v4.x + v4.y + v4.z + v4.w;
  float s2 = v4.x * v4.x + v4.y * v4.y + v4.z * v4.z + v4.w * v4.w;
#pragma unroll
  for (int d = 1; d < 64; d <<= 1) { s += __shfl_xor(s, d); s2 += __shfl_xor(s2, d); }
  __shared__ float ps[8];
  int lane = tid & 63, wave = tid >> 6;
  if (lane == 0) { ps[wave] = s; ps[4 + wave] = s2; }
  __syncthreads();
  float tot = ps[0] + ps[1] + ps[2] + ps[3];
  float tot2 = ps[4] + ps[5] + ps[6] + ps[7];
  float mean = tot * (1.f / 1024.f);
  float var = tot2 * (1.f / 1024.f) - mean * mean;
  float rstd = rsqrtf(var + 1e-5f);
  float4 gv = ((const float4*)gam)[tid];
  float4 bv = ((const float4*)bet)[tid];
  dst[(size_t)row * 256 + tid] = make_ushort4(
      f2b((v4.x - mean) * rstd * gv.x + bv.x), f2b((v4.y - mean) * rstd * gv.y + bv.y),
      f2b((v4.z - mean) * rstd * gv.z + bv.z), f2b((v4.w - mean) * rstd * gv.w + bv.w));
}

// ---------------- LayerNorm rows (bf16 in, bf16 out) — for O projection -----------
__global__ __launch_bounds__(256) void ln_rows(const ushort4* __restrict__ xin,
                                               const float* __restrict__ gam,
                                               const float* __restrict__ bet,
                                               ushort4* __restrict__ out) {
  int row = blockIdx.x, tid = threadIdx.x;
  ushort4 u = xin[(size_t)row * 256 + tid];
  float4 v;
  v.x = b2f(u.x); v.y = b2f(u.y); v.z = b2f(u.z); v.w = b2f(u.w);
  float s = v.x + v.y + v.z + v.w;
  float s2 = v.x * v.x + v.y * v.y + v.z * v.z + v.w * v.w;
#pragma unroll
  for (int d = 1; d < 64; d <<= 1) { s += __shfl_xor(s, d); s2 += __shfl_xor(s2, d); }
  __shared__ float ps[8];
  int lane = tid & 63, wave = tid >> 6;
  if (lane == 0) { ps[wave] = s; ps[4 + wave] = s2; }
  __syncthreads();
  float tot = ps[0] + ps[1] + ps[2] + ps[3];
  float tot2 = ps[4] + ps[5] + ps[6] + ps[7];
  float mean = tot * (1.f / 1024.f);
  float var = tot2 * (1.f / 1024.f) - mean * mean;
  float rstd = rsqrtf(var + 1e-5f);
  float4 gv = ((const float4*)gam)[tid];
  float4 bv = ((const float4*)bet)[tid];
  out[(size_t)row * 256 + tid] = make_ushort4(
      f2b((v.x - mean) * rstd * gv.x + bv.x), f2b((v.y - mean) * rstd * gv.y + bv.y),
      f2b((v.z - mean) * rstd * gv.z + bv.z), f2b((v.w - mean) * rstd * gv.w + bv.w));
}

// ---------------- fused QKV NT GEMM (blockIdx.y = mode 0/1/2) ---------------------
// mode 0 = Q (scaled by 0.125, rotary pos=l%256 -> qrot BHLd)
// mode 1 = K (rotary pos=256+l%256 -> krA; pos=l%256 -> krB; BHLd)
// mode 2 = V (bf16 transposed BHdL -> vT)
// 1536 blocks total -> 3+ blocks/CU queue with refill (barrier-drain overlap).
__global__ __launch_bounds__(256, 3) void gemm_qkv(
    const u16* __restrict__ Aq, const u16* __restrict__ Ak, const u16* __restrict__ Av,
    const u16* __restrict__ wbf,
    const float* __restrict__ bq, const float* __restrict__ bk, const float* __restrict__ bv,
    const float* __restrict__ ropc, const float* __restrict__ rops,
    u16* __restrict__ qrot, u16* __restrict__ krA, u16* __restrict__ krB,
    u16* __restrict__ vTp) {
  __shared__ __align__(16) u16 Als[128 * 64];
  __shared__ __align__(16) u16 Bls[128 * 64];
  const int tid = threadIdx.x, lane = tid & 63, wave = tid >> 6;
  const int g = lane >> 4, ln15 = lane & 15;
  const int mode = blockIdx.y;
  const u16* A = (mode == 0) ? Aq : (mode == 1) ? Ak : Av;
  const u16* Bw = wbf + (size_t)mode * 1048576;
  const float* bias = (mode == 0) ? bq : (mode == 1) ? bk : bv;
  // XCD-chunked swizzle on x (bijective; 512 blocks, 64 M-tiles x 8 N-tiles)
  const int bid = blockIdx.x;
  const int xcd = bid & 7, idx = bid >> 3;
  const int row0 = (xcd * 8 + (idx >> 3)) * 128;
  const int col0 = (idx & 7) * 128;
  const int wm = (wave >> 1) * 64, wn = (wave & 1) * 64;
  const int K = 1024;
  f32x4 acc[4][4] = {};

  for (int k0 = 0; k0 < K; k0 += 64) {
#pragma unroll
    for (int i = 0; i < 4; ++i) {  // A tile: 16KB, swizzled via pre-swizzled source
      int ch = i * 4 + wave;
      int olin = ch * 1024 + lane * 16;
      int r = olin >> 7;
      int cel = ((olin ^ ((r & 7) << 4)) >> 1) & 63;
      gload16(A + (size_t)(row0 + r) * K + k0 + cel, (char*)Als + ch * 1024);
    }
#pragma unroll
    for (int i = 0; i < 4; ++i) {  // B tile
      int ch = i * 4 + wave;
      int olin = ch * 1024 + lane * 16;
      int r = olin >> 7;
      int cel = ((olin ^ ((r & 7) << 4)) >> 1) & 63;
      gload16(Bw + (size_t)(col0 + r) * K + k0 + cel, (char*)Bls + ch * 1024);
    }
    __syncthreads();
#pragma unroll
    for (int ks = 0; ks < 2; ++ks) {
      bf16x8 af[4], bfv[4];
      int cb = (ks * 32 + g * 8) * 2;
#pragma unroll
      for (int mi = 0; mi < 4; ++mi) {
        int r = wm + mi * 16 + ln15;
        af[mi] = *(const bf16x8*)((const char*)Als + r * 128 + (cb ^ ((r & 7) << 4)));
      }
#pragma unroll
      for (int ni = 0; ni < 4; ++ni) {
        int r = wn + ni * 16 + ln15;
        bfv[ni] = *(const bf16x8*)((const char*)Bls + r * 128 + (cb ^ ((r & 7) << 4)));
      }
#pragma unroll
      for (int mi = 0; mi < 4; ++mi)
#pragma unroll
        for (int ni = 0; ni < 4; ++ni)
          acc[mi][ni] = MFMA16(af[mi], bfv[ni], acc[mi][ni]);
    }
    __syncthreads();
  }

#pragma unroll
  for (int mi = 0; mi < 4; ++mi)
#pragma unroll
    for (int ni = 0; ni < 4; ++ni)
#pragma unroll
      for (int r = 0; r < 4; ++r) {
        int row = row0 + wm + mi * 16 + g * 4 + r;
        int col = col0 + wn + ni * 16 + ln15;
        float val = acc[mi][ni][r] + bias[col];
        int bb = row >> 12, l = row & 4095, hh = col >> 6, d = col & 63;
        if (mode == 2) {
          vTp[(((size_t)bb * HEADS + hh) * HD + d) * LSEQ + l] = f2b(val);
        } else {
          if (mode == 0) val *= 0.125f;      // fold 1/sqrt(hd) into Q
          float oth = __shfl_xor(val, 1);    // rotary partner (adjacent dim = adjacent lane)
          int pB = l & 255;
          size_t oidx = (((size_t)bb * HEADS + hh) * LSEQ + l) * HD + d;
          if (mode == 0) {
            float cc = ropc[pB * 64 + d], ss = rops[pB * 64 + d];
            qrot[oidx] = f2b((d & 1) ? (val * cc + oth * ss) : (val * cc - oth * ss));
          } else {
            int pA = 256 + pB;
            float cA = ropc[pA * 64 + d], sA = rops[pA * 64 + d];
            krA[oidx] = f2b((d & 1) ? (val * cA + oth * sA) : (val * cA - oth * sA));
            float cB = ropc[pB * 64 + d], sB = rops[pB * 64 + d];
            krB[oidx] = f2b((d & 1) ? (val * cB + oth * sB) : (val * cB - oth * sB));
          }
        }
      }
}

// ---------------- final NT GEMM: out = LN(o) @ Wo^T + bias (f32) ------------------
__global__ __launch_bounds__(256, 3) void gemm_o(
    const u16* __restrict__ A, const u16* __restrict__ Bw, const float* __restrict__ bias,
    float* __restrict__ outf) {
  __shared__ __align__(16) u16 Als[128 * 64];
  __shared__ __align__(16) u16 Bls[128 * 64];
  const int tid = threadIdx.x, lane = tid & 63, wave = tid >> 6;
  const int g = lane >> 4, ln15 = lane & 15;
  const int bid = blockIdx.x;
  const int xcd = bid & 7, idx = bid >> 3;
  const int row0 = (xcd * 8 + (idx >> 3)) * 128;
  const int col0 = (idx & 7) * 128;
  const int wm = (wave >> 1) * 64, wn = (wave & 1) * 64;
  const int K = 1024, N = 1024;
  f32x4 acc[4][4] = {};

  for (int k0 = 0; k0 < K; k0 += 64) {
#pragma unroll
    for (int i = 0; i < 4; ++i) {
      int ch = i * 4 + wave;
      int olin = ch * 1024 + lane * 16;
      int r = olin >> 7;
      int cel = ((olin ^ ((r & 7) << 4)) >> 1) & 63;
      gload16(A + (size_t)(row0 + r) * K + k0 + cel, (char*)Als + ch * 1024);
    }
#pragma unroll
    for (int i = 0; i < 4; ++i) {
      int ch = i * 4 + wave;
      int olin = ch * 1024 + lane * 16;
      int r = olin >> 7;
      int cel = ((olin ^ ((r & 7) << 4)) >> 1) & 63;
      gload16(Bw + (size_t)(col0 + r) * K + k0 + cel, (char*)Bls + ch * 1024);
    }
    __syncthreads();
#pragma unroll
    for (int ks = 0; ks < 2; ++ks) {
      bf16x8 af[4], bfv[4];
      int cb = (ks * 32 + g * 8) * 2;
#pragma unroll
      for (int mi = 0; mi < 4; ++mi) {
        int r = wm + mi * 16 + ln15;
        af[mi] = *(const bf16x8*)((const char*)Als + r * 128 + (cb ^ ((r & 7) << 4)));
      }
#pragma unroll
      for (int ni = 0; ni < 4; ++ni) {
        int r = wn + ni * 16 + ln15;
        bfv[ni] = *(const bf16x8*)((const char*)Bls + r * 128 + (cb ^ ((r & 7) << 4)));
      }
#pragma unroll
      for (int mi = 0; mi < 4; ++mi)
#pragma unroll
        for (int ni = 0; ni < 4; ++ni)
          acc[mi][ni] = MFMA16(af[mi], bfv[ni], acc[mi][ni]);
    }
    __syncthreads();
  }

#pragma unroll
  for (int mi = 0; mi < 4; ++mi)
#pragma unroll
    for (int ni = 0; ni < 4; ++ni)
#pragma unroll
      for (int r = 0; r < 4; ++r) {
        int row = row0 + wm + mi * 16 + g * 4 + r;
        int col = col0 + wn + ni * 16 + ln15;
        outf[(size_t)row * N + col] = acc[mi][ni][r] + bias[col];
      }
}

// ---------------- fused windowed attention (v5: cell-interval chunk skip) ---------
// block = (b, h, bucket); 8 waves x 32 q-rows; K staged 128 cols/stage, dbuf.
// cell is SORTED per batch -> equality regions are intervals; disjoint cell ranges
// between a wave's rows and a chunk's cols => chunk fully masked => skip (exact).
__global__ __launch_bounds__(512, 2) void attn_kernel(
    const u16* __restrict__ qrot,   // (B,H,L,64) rotated, pre-scaled by 0.125
    const u16* __restrict__ krotA,  // (B,H,L,64) rotated (current-bucket view)
    const u16* __restrict__ krotB,  // (B,H,L,64) rotated (prev-bucket view)
    const u16* __restrict__ vT,     // (B,H,64,L)
    const int* __restrict__ cell,   // (B,L)
    u16* __restrict__ o) {          // (B,L,1024) bf16
  __shared__ __align__(16) u16 Kc[2][128 * 64];  // dbuf K stages, swizzled, 2x16KB
  __shared__ __align__(16) u16 Pl[8 * 32 * 64];  // per-wave P relay, swizzled, 32KB
  __shared__ int ci[256];
  __shared__ int cj[512];

  const int tid = threadIdx.x, lane = tid & 63, wave = tid >> 6;
  const int g = lane >> 4, ln15 = lane & 15;
  const int bucket = blockIdx.x & 15;
  const int h = (blockIdx.x >> 4) & 15;
  const int b = blockIdx.x >> 8;
  const int w0 = bucket * 256;
  const size_t base = (size_t)(b * HEADS + h) * LSEQ * HD;

  if (tid < 256) ci[tid] = cell[b * LSEQ + w0 + tid];
  {
    int gj = w0 - 256 + tid;
    cj[tid] = (gj >= 0) ? cell[b * LSEQ + gj] : (int)0x80000000;
  }

  // Q fragments (already rotated + scaled): rows w0 + wave*32 + mi*16 + ln15
  bf16x8 qf[2][2];
#pragma unroll
  for (int mi = 0; mi < 2; ++mi)
#pragma unroll
    for (int ks = 0; ks < 2; ++ks)
      qf[mi][ks] = *(const bf16x8*)(qrot + base +
          (size_t)(w0 + wave * 32 + mi * 16 + ln15) * HD + ks * 32 + g * 8);

  f32x4 Oa[2][4] = {};
  float mrow[2][4], lrow[2][4];
#pragma unroll
  for (int a1 = 0; a1 < 2; ++a1)
#pragma unroll
    for (int a2 = 0; a2 < 4; ++a2) { mrow[a1][a2] = NEGF; lrow[a1][a2] = 0.f; }

#define STAGE_K(bi, s)                                                          \
  {                                                                             \
    const u16* ksrc_ = ((s) < 2) ? krotB : krotA;                               \
    int gj0_ = w0 - 256 + (s) * 128;                                            \
    _Pragma("unroll")                                                           \
    for (int i_ = 0; i_ < 2; ++i_) {                                            \
      int ch_ = i_ * 8 + wave;                                                  \
      int olin_ = ch_ * 1024 + lane * 16;                                       \
      int r_ = olin_ >> 7;                                                      \
      int cel_ = ((olin_ ^ ((r_ & 7) << 4)) >> 1) & 63;                         \
      gload16(ksrc_ + base + (size_t)(gj0_ + r_) * HD + cel_,                   \
              (char*)Kc[bi] + ch_ * 1024);                                      \
    }                                                                           \
  }

  const int s0 = (bucket == 0) ? 2 : 0;
  STAGE_K(0, s0);
  __syncthreads();  // stage s0 ready; ci/cj visible

  // cell intervals (sorted): block rows, this wave's rows
  const int crb_lo = ci[0], crb_hi = ci[255];
  const int crw_lo = ci[wave * 32], crw_hi = ci[wave * 32 + 31];

  for (int s = s0; s < 4; ++s) {
    const int cur = (s - s0) & 1;
    if (s + 1 < 4) {
      // block-level staging skip: stage needed iff any of its 2 chunks' cell range
      // intersects the block's row range (block skip => every wave skips it)
      int k1 = (s + 1) * 2;
      bool need = false;
#pragma unroll
      for (int kk = 0; kk < 2; ++kk) {
        int clo = cj[(k1 + kk) * 64], chi = cj[(k1 + kk) * 64 + 63];
        need = need || !(chi < crb_lo || clo > crb_hi);
      }
      if (need) STAGE_K(cur ^ 1, s + 1);
    }

    // two 64-col sub-chunks within this stage
#pragma unroll
    for (int sub = 0; sub < 2; ++sub) {
      const int k = s * 2 + sub;                   // 64-col chunk index 0..7
      if (k * 64 > wave * 32 + 287) continue;      // causal: no col in chunk reachable
      {                                            // cell-interval skip (exact)
        int clo = cj[k * 64], chi = cj[k * 64 + 63];
        if (chi < crw_lo || clo > crw_hi) continue;
      }
      const int gj0 = w0 - 256 + k * 64;           // global col base of chunk
      const int lr0 = sub * 64;                    // local row base in Kc stage

#pragma unroll
      for (int mi = 0; mi < 2; ++mi) {
        f32x4 sc[4] = {};
        __builtin_amdgcn_s_setprio(1);
#pragma unroll
        for (int ks = 0; ks < 2; ++ks) {
          int cb = (ks * 32 + g * 8) * 2;
#pragma unroll
          for (int ni = 0; ni < 4; ++ni) {
            int r = lr0 + ni * 16 + ln15;
            bf16x8 kf = *(const bf16x8*)((const char*)Kc[cur] + r * 128 + (cb ^ ((r & 7) << 4)));
            sc[ni] = MFMA16(qf[mi][ks], kf, sc[ni]);
          }
        }
        __builtin_amdgcn_s_setprio(0);
        // mask + row max (scores pre-scaled via Q)
        float mx[4] = {NEGF, NEGF, NEGF, NEGF};
#pragma unroll
        for (int ni = 0; ni < 4; ++ni)
#pragma unroll
          for (int r = 0; r < 4; ++r) {
            int iloc = wave * 32 + mi * 16 + g * 4 + r;
            int p = k * 64 + ni * 16 + ln15;
            bool ok = (p <= iloc + 256) && (ci[iloc] == cj[p]);
            float sv = ok ? sc[ni][r] : NEGF;
            sc[ni][r] = sv;
            mx[r] = fmaxf(mx[r], sv);
          }
#pragma unroll
        for (int d = 1; d < 16; d <<= 1)
#pragma unroll
          for (int r = 0; r < 4; ++r) mx[r] = fmaxf(mx[r], __shfl_xor(mx[r], d));
        float rs[4] = {0.f, 0.f, 0.f, 0.f};
        // T13 defer-max: rescale only if max grew by > 8
        bool big = false;
#pragma unroll
        for (int r = 0; r < 4; ++r) big = big || (mx[r] > mrow[mi][r] + 8.0f);
        if (__any(big)) {
#pragma unroll
          for (int r = 0; r < 4; ++r) {
            float mold = mrow[mi][r];
            float mnew = fmaxf(mold, mx[r]);
            float alpha = __expf(mold - mnew);  // NEG,NEG -> 1; NEG,finite -> 0
            mrow[mi][r] = mnew;
            lrow[mi][r] *= alpha;
#pragma unroll
            for (int nd = 0; nd < 4; ++nd) Oa[mi][nd][r] *= alpha;
          }
        }
#pragma unroll
        for (int ni = 0; ni < 4; ++ni)
#pragma unroll
          for (int r = 0; r < 4; ++r) {
            float sv = sc[ni][r];
            float p = (sv > NEGF * 0.5f) ? __expf(sv - mrow[mi][r]) : 0.f;
            rs[r] += p;
            int row = mi * 16 + g * 4 + r;
            int colb = (ni * 16 + ln15) * 2;
            *(u16*)((char*)Pl + wave * 4096 + row * 128 + (colb ^ ((row & 7) << 4))) = f2b(p);
          }
#pragma unroll
        for (int d = 1; d < 16; d <<= 1)
#pragma unroll
          for (int r = 0; r < 4; ++r) rs[r] += __shfl_xor(rs[r], d);
#pragma unroll
        for (int r = 0; r < 4; ++r) lrow[mi][r] += rs[r];
      }  // mi

      // PV: O += P(32x64) * V(64x64); V fragments direct from global
#pragma unroll
      for (int jb = 0; jb < 2; ++jb) {
        bf16x8 pa[2], vb[4];
        int cb = (jb * 32 + g * 8) * 2;
#pragma unroll
        for (int mi = 0; mi < 2; ++mi) {
          int row = mi * 16 + ln15;
          pa[mi] = *(const bf16x8*)((const char*)Pl + wave * 4096 + row * 128 + (cb ^ ((row & 7) << 4)));
        }
#pragma unroll
        for (int nd = 0; nd < 4; ++nd) {
          int d = nd * 16 + ln15;
          int p0 = gj0 + jb * 32 + g * 8;
          vb[nd] = *(const bf16x8*)(vT + base + (size_t)d * LSEQ + p0);
        }
        __builtin_amdgcn_s_setprio(1);
#pragma unroll
        for (int mi = 0; mi < 2; ++mi)
#pragma unroll
          for (int nd = 0; nd < 4; ++nd) Oa[mi][nd] = MFMA16(pa[mi], vb[nd], Oa[mi][nd]);
        __builtin_amdgcn_s_setprio(0);
      }
    }  // sub

    __syncthreads();  // stage s+1 writes complete + all readers of Kc[cur] done
  }  // stages

  // epilogue: normalize and store
#pragma unroll
  for (int mi = 0; mi < 2; ++mi)
#pragma unroll
    for (int r = 0; r < 4; ++r) {
      float invl = 1.0f / lrow[mi][r];
      int gi = w0 + wave * 32 + mi * 16 + g * 4 + r;
      size_t ob = ((size_t)b * LSEQ + gi) * DM + h * HD;
#pragma unroll
      for (int nd = 0; nd < 4; ++nd) o[ob + nd * 16 + ln15] = f2b(Oa[mi][nd][r] * invl);
    }
#undef STAGE_K
}

extern "C" void kernel_launch(void* const* d_in, const int* in_sizes, int n_in,
                              void* d_out, int out_size, void* d_ws, size_t ws_size,
                              hipStream_t stream) {
  const float* q = (const float*)d_in[0];
  const float* k = (const float*)d_in[1];
  const float* v = (const float*)d_in[2];
  const int* cell = (const int*)d_in[3];
  const float* lnw[4] = {(const float*)d_in[4], (const float*)d_in[8], (const float*)d_in[12], (const float*)d_in[16]};
  const float* lnb[4] = {(const float*)d_in[5], (const float*)d_in[9], (const float*)d_in[13], (const float*)d_in[17]};
  const float* Wm[4]  = {(const float*)d_in[6], (const float*)d_in[10], (const float*)d_in[14], (const float*)d_in[18]};
  const float* bi[4]  = {(const float*)d_in[7], (const float*)d_in[11], (const float*)d_in[15], (const float*)d_in[19]};

  char* ws = (char*)d_ws;
  u16* xlnq  = (u16*)(ws);               // 16 MiB: LN'd q (also reused for LN(o))
  u16* wbf   = (u16*)(ws + 16777216);    // 8 MiB: 4 bf16 weights
  u16* qrot  = (u16*)(ws + 25165824);    // 16 MiB
  u16* krA   = (u16*)(ws + 41943040);    // 16 MiB
  u16* krB   = (u16*)(ws + 58720256);    // 16 MiB
  u16* vT    = (u16*)(ws + 75497472);    // 16 MiB
  u16* obuf  = (u16*)(ws + 92274688);    // 16 MiB: xln_k, then attn output
  float* ropc = (float*)(ws + 109051904);
  float* rops = (float*)(ws + 109182976);  // end ~104.3 MiB
  u16* xlnk = obuf;                      // alias: free until attn writes
  u16* xlnv = (u16*)d_out;               // scratch in d_out (fully overwritten by gemm_o)

  cvtw<<<1024, 256, 0, stream>>>((const float4*)Wm[0], (const float4*)Wm[1],
                                 (const float4*)Wm[2], (const float4*)Wm[3], (ushort4*)wbf);
  rope_build<<<512, 64, 0, stream>>>(ropc, rops);

  dim3 lng(8192, 3);
  ln_qkv<<<lng, 256, 0, stream>>>((const float4*)q, (const float4*)k, (const float4*)v,
                                  lnw[0], lnb[0], lnw[1], lnb[1], lnw[2], lnb[2],
                                  (ushort4*)xlnq, (ushort4*)xlnk, (ushort4*)xlnv);
  dim3 gq(512, 3);
  gemm_qkv<<<gq, 256, 0, stream>>>(xlnq, xlnk, xlnv, wbf, bi[0], bi[1], bi[2],
                                   ropc, rops, qrot, krA, krB, vT);
  attn_kernel<<<512, 512, 0, stream>>>(qrot, krA, krB, vT, cell, obuf);
  ln_rows<<<8192, 256, 0, stream>>>((const ushort4*)obuf, lnw[3], lnb[3], (ushort4*)xlnq);
  gemm_o<<<512, 256, 0, stream>>>(xlnq, wbf + 3145728, bi[3], (float*)d_out);
}

// Round 9
// 198.109 us; speedup vs baseline: 1.3956x; 1.0835x over previous
//
#include <hip/hip_runtime.h>

#define HEADS 16
#define HD 64
#define DM 1024
#define LSEQ 4096
#define NEGF (-1.0e30f)

typedef __attribute__((ext_vector_type(8))) short bf16x8;
typedef __attribute__((ext_vector_type(4))) float f32x4;
typedef unsigned short u16;

#define MFMA16(a, b, c) __builtin_amdgcn_mfma_f32_16x16x32_bf16((a), (b), (c), 0, 0, 0)

static __device__ __forceinline__ float b2f(u16 u) {
  union { float f; unsigned i; } t; t.i = ((unsigned)u) << 16; return t.f;
}
static __device__ __forceinline__ u16 f2b(float f) {
  union { float f; unsigned i; } t; t.f = f;
  unsigned r = t.i + 0x7fffu + ((t.i >> 16) & 1u);
  return (u16)(r >> 16);
}
static __device__ __forceinline__ ushort4 pk4(float4 v) {
  return make_ushort4(f2b(v.x), f2b(v.y), f2b(v.z), f2b(v.w));
}
static __device__ __forceinline__ void gload16(const void* g, void* l) {
  __builtin_amdgcn_global_load_lds((const __attribute__((address_space(1))) void*)g,
                                   (__attribute__((address_space(3))) void*)l, 16, 0, 0);
}

// ---------------- rope tables: cos/sin for window positions 0..511, dims 0..63 ----
__global__ void rope_build(float* __restrict__ ropc, float* __restrict__ rops) {
  int p = blockIdx.x, d = threadIdx.x;
  int t2 = d & ~1;
  double inv = pow(10000.0, -(double)t2 / 64.0);
  double f = (double)p * inv;
  ropc[p * 64 + d] = (float)cos(f);
  rops[p * 64 + d] = (float)sin(f);
}

// ---------------- weights f32 -> bf16 (4 at once) ----------------
__global__ void cvtw(const float4* __restrict__ a, const float4* __restrict__ b,
                     const float4* __restrict__ c, const float4* __restrict__ d,
                     ushort4* __restrict__ out) {
  int i = blockIdx.x * blockDim.x + threadIdx.x;  // 0..262143 (float4 units of 1M elems)
  out[i]          = pk4(a[i]);
  out[i + 262144] = pk4(b[i]);
  out[i + 524288] = pk4(c[i]);
  out[i + 786432] = pk4(d[i]);
}

// ---------------- fused LayerNorm for q,k,v (f32 in, bf16 out) --------------------
__global__ __launch_bounds__(256) void ln_qkv(
    const float4* __restrict__ q, const float4* __restrict__ k, const float4* __restrict__ v,
    const float* __restrict__ g0, const float* __restrict__ b0,
    const float* __restrict__ g1, const float* __restrict__ b1,
    const float* __restrict__ g2, const float* __restrict__ b2,
    ushort4* __restrict__ o0, ushort4* __restrict__ o1, ushort4* __restrict__ o2) {
  const int row = blockIdx.x, tid = threadIdx.x, sel = blockIdx.y;
  const float4* src = (sel == 0) ? q : (sel == 1) ? k : v;
  const float* gam = (sel == 0) ? g0 : (sel == 1) ? g1 : g2;
  const float* bet = (sel == 0) ? b0 : (sel == 1) ? b1 : b2;
  ushort4* dst = (sel == 0) ? o0 : (sel == 1) ? o1 : o2;

  float4 v4 = src[(size_t)row * 256 + tid];
  float s = v4.x + v4.y + v4.z + v4.w;
  float s2 = v4.x * v4.x + v4.y * v4.y + v4.z * v4.z + v4.w * v4.w;
#pragma unroll
  for (int d = 1; d < 64; d <<= 1) { s += __shfl_xor(s, d); s2 += __shfl_xor(s2, d); }
  __shared__ float ps[8];
  int lane = tid & 63, wave = tid >> 6;
  if (lane == 0) { ps[wave] = s; ps[4 + wave] = s2; }
  __syncthreads();
  float tot = ps[0] + ps[1] + ps[2] + ps[3];
  float tot2 = ps[4] + ps[5] + ps[6] + ps[7];
  float mean = tot * (1.f / 1024.f);
  float var = tot2 * (1.f / 1024.f) - mean * mean;
  float rstd = rsqrtf(var + 1e-5f);
  float4 gv = ((const float4*)gam)[tid];
  float4 bv = ((const float4*)bet)[tid];
  dst[(size_t)row * 256 + tid] = make_ushort4(
      f2b((v4.x - mean) * rstd * gv.x + bv.x), f2b((v4.y - mean) * rstd * gv.y + bv.y),
      f2b((v4.z - mean) * rstd * gv.z + bv.z), f2b((v4.w - mean) * rstd * gv.w + bv.w));
}

// ---------------- LayerNorm rows (bf16 in, bf16 out) — for O projection -----------
__global__ __launch_bounds__(256) void ln_rows(const ushort4* __restrict__ xin,
                                               const float* __restrict__ gam,
                                               const float* __restrict__ bet,
                                               ushort4* __restrict__ out) {
  int row = blockIdx.x, tid = threadIdx.x;
  ushort4 u = xin[(size_t)row * 256 + tid];
  float4 v;
  v.x = b2f(u.x); v.y = b2f(u.y); v.z = b2f(u.z); v.w = b2f(u.w);
  float s = v.x + v.y + v.z + v.w;
  float s2 = v.x * v.x + v.y * v.y + v.z * v.z + v.w * v.w;
#pragma unroll
  for (int d = 1; d < 64; d <<= 1) { s += __shfl_xor(s, d); s2 += __shfl_xor(s2, d); }
  __shared__ float ps[8];
  int lane = tid & 63, wave = tid >> 6;
  if (lane == 0) { ps[wave] = s; ps[4 + wave] = s2; }
  __syncthreads();
  float tot = ps[0] + ps[1] + ps[2] + ps[3];
  float tot2 = ps[4] + ps[5] + ps[6] + ps[7];
  float mean = tot * (1.f / 1024.f);
  float var = tot2 * (1.f / 1024.f) - mean * mean;
  float rstd = rsqrtf(var + 1e-5f);
  float4 gv = ((const float4*)gam)[tid];
  float4 bv = ((const float4*)bet)[tid];
  out[(size_t)row * 256 + tid] = make_ushort4(
      f2b((v.x - mean) * rstd * gv.x + bv.x), f2b((v.y - mean) * rstd * gv.y + bv.y),
      f2b((v.z - mean) * rstd * gv.z + bv.z), f2b((v.w - mean) * rstd * gv.w + bv.w));
}

// ---------------- fused QKV NT GEMM (blockIdx.y = mode 0/1/2) ---------------------
// mode 0 = Q (scaled 0.125, rotary pos=l%256 -> qrot BHLd)
// mode 1 = K (rotary pos=256+l%256 -> krot BHLd; single view — prev view derived in attn)
// mode 2 = V (bf16 transposed BHdL -> vT)
// Epilogue stages C through LDS (overlaying Als/Bls) -> 16B coalesced stores.
__global__ __launch_bounds__(256, 3) void gemm_qkv(
    const u16* __restrict__ Aq, const u16* __restrict__ Ak, const u16* __restrict__ Av,
    const u16* __restrict__ wbf,
    const float* __restrict__ bq, const float* __restrict__ bk, const float* __restrict__ bv,
    const float* __restrict__ ropc, const float* __restrict__ rops,
    u16* __restrict__ qrot, u16* __restrict__ krot, u16* __restrict__ vTp) {
  __shared__ __align__(16) char smem[34816];  // staging 32KB; epilogue C-tile 128x136 u16
  u16* Als = (u16*)smem;
  u16* Bls = (u16*)(smem + 16384);
  const int tid = threadIdx.x, lane = tid & 63, wave = tid >> 6;
  const int g = lane >> 4, ln15 = lane & 15;
  const int mode = blockIdx.y;
  const u16* A = (mode == 0) ? Aq : (mode == 1) ? Ak : Av;
  const u16* Bw = wbf + (size_t)mode * 1048576;
  const float* bias = (mode == 0) ? bq : (mode == 1) ? bk : bv;
  // XCD-chunked swizzle on x (bijective; 512 blocks, 64 M-tiles x 8 N-tiles)
  const int bid = blockIdx.x;
  const int xcd = bid & 7, idx = bid >> 3;
  const int row0 = (xcd * 8 + (idx >> 3)) * 128;
  const int col0 = (idx & 7) * 128;
  const int wm = (wave >> 1) * 64, wn = (wave & 1) * 64;
  const int K = 1024;
  f32x4 acc[4][4] = {};

  for (int k0 = 0; k0 < K; k0 += 64) {
#pragma unroll
    for (int i = 0; i < 4; ++i) {  // A tile: 16KB, swizzled via pre-swizzled source
      int ch = i * 4 + wave;
      int olin = ch * 1024 + lane * 16;
      int r = olin >> 7;
      int cel = ((olin ^ ((r & 7) << 4)) >> 1) & 63;
      gload16(A + (size_t)(row0 + r) * K + k0 + cel, (char*)Als + ch * 1024);
    }
#pragma unroll
    for (int i = 0; i < 4; ++i) {  // B tile
      int ch = i * 4 + wave;
      int olin = ch * 1024 + lane * 16;
      int r = olin >> 7;
      int cel = ((olin ^ ((r & 7) << 4)) >> 1) & 63;
      gload16(Bw + (size_t)(col0 + r) * K + k0 + cel, (char*)Bls + ch * 1024);
    }
    __syncthreads();
#pragma unroll
    for (int ks = 0; ks < 2; ++ks) {
      bf16x8 af[4], bfv[4];
      int cb = (ks * 32 + g * 8) * 2;
#pragma unroll
      for (int mi = 0; mi < 4; ++mi) {
        int r = wm + mi * 16 + ln15;
        af[mi] = *(const bf16x8*)((const char*)Als + r * 128 + (cb ^ ((r & 7) << 4)));
      }
#pragma unroll
      for (int ni = 0; ni < 4; ++ni) {
        int r = wn + ni * 16 + ln15;
        bfv[ni] = *(const bf16x8*)((const char*)Bls + r * 128 + (cb ^ ((r & 7) << 4)));
      }
#pragma unroll
      for (int mi = 0; mi < 4; ++mi)
#pragma unroll
        for (int ni = 0; ni < 4; ++ni)
          acc[mi][ni] = MFMA16(af[mi], bfv[ni], acc[mi][ni]);
    }
    __syncthreads();
  }

  // ---- epilogue: rotary (f32, single rounding) + LDS-staged coalesced writes ----
  u16* Cl = (u16*)smem;  // 128 x 136 u16 (stride 272B: 16B-aligned rows, bank-spread)
#pragma unroll
  for (int mi = 0; mi < 4; ++mi)
#pragma unroll
    for (int ni = 0; ni < 4; ++ni)
#pragma unroll
      for (int r = 0; r < 4; ++r) {
        int rowc = wm + mi * 16 + g * 4 + r;
        int colc = wn + ni * 16 + ln15;
        int row = row0 + rowc, col = col0 + colc;
        float val = acc[mi][ni][r] + bias[col];
        if (mode == 2) {
          Cl[colc * 136 + rowc] = f2b(val);  // transposed store for (B,H,d,L) out
        } else {
          if (mode == 0) val *= 0.125f;      // fold 1/sqrt(hd) into Q
          float oth = __shfl_xor(val, 1);    // rotary partner (adjacent dim = adjacent lane)
          int d = col & 63;
          int pp = (row & 255) + ((mode == 1) ? 256 : 0);
          float cc = ropc[pp * 64 + d], ss = rops[pp * 64 + d];
          Cl[rowc * 136 + colc] = f2b((d & 1) ? (val * cc + oth * ss) : (val * cc - oth * ss));
        }
      }
  __syncthreads();
  if (mode == 2) {
#pragma unroll
    for (int i = 0; i < 8; ++i) {
      int c2 = i * 256 + tid;
      int dloc = c2 >> 4, lgrp = c2 & 15;
      bf16x8 vv = *(const bf16x8*)(Cl + dloc * 136 + lgrp * 8);
      int colg = col0 + dloc, hh = colg >> 6, d = colg & 63;
      int l = row0 + lgrp * 8, bb = l >> 12, ll = l & 4095;
      *(bf16x8*)(vTp + (((size_t)bb * HEADS + hh) * HD + d) * LSEQ + ll) = vv;
    }
  } else {
    u16* dst = (mode == 0) ? qrot : krot;
#pragma unroll
    for (int i = 0; i < 8; ++i) {
      int c2 = i * 256 + tid;
      int rowc = c2 >> 4, cgrp = c2 & 15;
      bf16x8 vv = *(const bf16x8*)(Cl + rowc * 136 + cgrp * 8);
      int l = row0 + rowc, bb = l >> 12, ll = l & 4095;
      int colg = col0 + cgrp * 8, hh = colg >> 6, d0 = colg & 63;
      *(bf16x8*)(dst + (((size_t)bb * HEADS + hh) * LSEQ + ll) * HD + d0) = vv;
    }
  }
}

// ---------------- final NT GEMM: out = LN(o) @ Wo^T + bias (f32) ------------------
__global__ __launch_bounds__(256, 3) void gemm_o(
    const u16* __restrict__ A, const u16* __restrict__ Bw, const float* __restrict__ bias,
    float* __restrict__ outf) {
  __shared__ __align__(16) u16 Als[128 * 64];
  __shared__ __align__(16) u16 Bls[128 * 64];
  const int tid = threadIdx.x, lane = tid & 63, wave = tid >> 6;
  const int g = lane >> 4, ln15 = lane & 15;
  const int bid = blockIdx.x;
  const int xcd = bid & 7, idx = bid >> 3;
  const int row0 = (xcd * 8 + (idx >> 3)) * 128;
  const int col0 = (idx & 7) * 128;
  const int wm = (wave >> 1) * 64, wn = (wave & 1) * 64;
  const int K = 1024, N = 1024;
  f32x4 acc[4][4] = {};

  for (int k0 = 0; k0 < K; k0 += 64) {
#pragma unroll
    for (int i = 0; i < 4; ++i) {
      int ch = i * 4 + wave;
      int olin = ch * 1024 + lane * 16;
      int r = olin >> 7;
      int cel = ((olin ^ ((r & 7) << 4)) >> 1) & 63;
      gload16(A + (size_t)(row0 + r) * K + k0 + cel, (char*)Als + ch * 1024);
    }
#pragma unroll
    for (int i = 0; i < 4; ++i) {
      int ch = i * 4 + wave;
      int olin = ch * 1024 + lane * 16;
      int r = olin >> 7;
      int cel = ((olin ^ ((r & 7) << 4)) >> 1) & 63;
      gload16(Bw + (size_t)(col0 + r) * K + k0 + cel, (char*)Bls + ch * 1024);
    }
    __syncthreads();
#pragma unroll
    for (int ks = 0; ks < 2; ++ks) {
      bf16x8 af[4], bfv[4];
      int cb = (ks * 32 + g * 8) * 2;
#pragma unroll
      for (int mi = 0; mi < 4; ++mi) {
        int r = wm + mi * 16 + ln15;
        af[mi] = *(const bf16x8*)((const char*)Als + r * 128 + (cb ^ ((r & 7) << 4)));
      }
#pragma unroll
      for (int ni = 0; ni < 4; ++ni) {
        int r = wn + ni * 16 + ln15;
        bfv[ni] = *(const bf16x8*)((const char*)Bls + r * 128 + (cb ^ ((r & 7) << 4)));
      }
#pragma unroll
      for (int mi = 0; mi < 4; ++mi)
#pragma unroll
        for (int ni = 0; ni < 4; ++ni)
          acc[mi][ni] = MFMA16(af[mi], bfv[ni], acc[mi][ni]);
    }
    __syncthreads();
  }

#pragma unroll
  for (int mi = 0; mi < 4; ++mi)
#pragma unroll
    for (int ni = 0; ni < 4; ++ni)
#pragma unroll
      for (int r = 0; r < 4; ++r) {
        int row = row0 + wm + mi * 16 + g * 4 + r;
        int col = col0 + wn + ni * 16 + ln15;
        outf[(size_t)row * N + col] = acc[mi][ni][r] + bias[col];
      }
}

// ---------------- fused windowed attention (v6: single-K, derived prev-view Q) ----
// block = (b, h, bucket); 8 waves x 32 q-rows; K staged 128 cols/stage, dbuf.
// krot holds R(256+p)k; for prev-bucket chunks use q~ = R(256)*qrot (rotation
// composition: <R(i)q, R(p)k> == <R(256+i)q, R(256+p)k>). cell sorted -> interval skip.
__global__ __launch_bounds__(512, 2) void attn_kernel(
    const u16* __restrict__ qrot,   // (B,H,L,64) rotated by R(l%256), scaled 0.125
    const u16* __restrict__ krot,   // (B,H,L,64) rotated by R(256+l%256)
    const u16* __restrict__ vT,     // (B,H,64,L)
    const int* __restrict__ cell,   // (B,L)
    const float* __restrict__ ropc, const float* __restrict__ rops,
    u16* __restrict__ o) {          // (B,L,1024) bf16
  __shared__ __align__(16) u16 Kc[2][128 * 64];  // dbuf K stages, swizzled, 2x16KB
  __shared__ __align__(16) u16 Pl[8 * 32 * 64];  // per-wave P relay, swizzled, 32KB
  __shared__ int ci[256];
  __shared__ int cj[512];

  const int tid = threadIdx.x, lane = tid & 63, wave = tid >> 6;
  const int g = lane >> 4, ln15 = lane & 15;
  const int bucket = blockIdx.x & 15;
  const int h = (blockIdx.x >> 4) & 15;
  const int b = blockIdx.x >> 8;
  const int w0 = bucket * 256;
  const size_t base = (size_t)(b * HEADS + h) * LSEQ * HD;

  if (tid < 256) ci[tid] = cell[b * LSEQ + w0 + tid];
  {
    int gj = w0 - 256 + tid;
    cj[tid] = (gj >= 0) ? cell[b * LSEQ + gj] : (int)0x80000000;
  }

  // Q fragments (already rotated + scaled): rows w0 + wave*32 + mi*16 + ln15
  bf16x8 qf[2][2];
#pragma unroll
  for (int mi = 0; mi < 2; ++mi)
#pragma unroll
    for (int ks = 0; ks < 2; ++ks)
      qf[mi][ks] = *(const bf16x8*)(qrot + base +
          (size_t)(w0 + wave * 32 + mi * 16 + ln15) * HD + ks * 32 + g * 8);

  // prev-view Q: q~ = R(256) * qf (fixed-angle in-register rotation, once per block)
  bf16x8 qfB[2][2];
#pragma unroll
  for (int ks = 0; ks < 2; ++ks) {
    const int d0 = ks * 32 + g * 8;
    float rc[8], rs8[8];
#pragma unroll
    for (int j = 0; j < 8; ++j) {
      rc[j] = ropc[256 * 64 + d0 + j];
      rs8[j] = rops[256 * 64 + d0 + j];
    }
#pragma unroll
    for (int mi = 0; mi < 2; ++mi) {
      bf16x8 s = qf[mi][ks], t;
#pragma unroll
      for (int j = 0; j < 8; j += 2) {
        float e = b2f((u16)s[j]), od = b2f((u16)s[j + 1]);
        t[j]     = (short)f2b(e * rc[j] - od * rs8[j]);
        t[j + 1] = (short)f2b(e * rs8[j] + od * rc[j]);
      }
      qfB[mi][ks] = t;
    }
  }

  f32x4 Oa[2][4] = {};
  float mrow[2][4], lrow[2][4];
#pragma unroll
  for (int a1 = 0; a1 < 2; ++a1)
#pragma unroll
    for (int a2 = 0; a2 < 4; ++a2) { mrow[a1][a2] = NEGF; lrow[a1][a2] = 0.f; }

#define STAGE_K(bi, s)                                                          \
  {                                                                             \
    int gj0_ = w0 - 256 + (s) * 128;                                            \
    _Pragma("unroll")                                                           \
    for (int i_ = 0; i_ < 2; ++i_) {                                            \
      int ch_ = i_ * 8 + wave;                                                  \
      int olin_ = ch_ * 1024 + lane * 16;                                       \
      int r_ = olin_ >> 7;                                                      \
      int cel_ = ((olin_ ^ ((r_ & 7) << 4)) >> 1) & 63;                         \
      gload16(krot + base + (size_t)(gj0_ + r_) * HD + cel_,                    \
              (char*)Kc[bi] + ch_ * 1024);                                      \
    }                                                                           \
  }

  const int s0 = (bucket == 0) ? 2 : 0;
  STAGE_K(0, s0);
  __syncthreads();  // stage s0 ready; ci/cj visible

  // cell intervals (sorted): block rows, this wave's rows
  const int crb_lo = ci[0], crb_hi = ci[255];
  const int crw_lo = ci[wave * 32], crw_hi = ci[wave * 32 + 31];

  for (int s = s0; s < 4; ++s) {
    const int cur = (s - s0) & 1;
    if (s + 1 < 4) {
      // block-level staging skip: stage needed iff any of its 2 chunks' cell range
      // intersects the block's row range (block skip => every wave skips it)
      int k1 = (s + 1) * 2;
      bool need = false;
#pragma unroll
      for (int kk = 0; kk < 2; ++kk) {
        int clo = cj[(k1 + kk) * 64], chi = cj[(k1 + kk) * 64 + 63];
        need = need || !(chi < crb_lo || clo > crb_hi);
      }
      if (need) STAGE_K(cur ^ 1, s + 1);
    }

    // two 64-col sub-chunks within this stage
#pragma unroll
    for (int sub = 0; sub < 2; ++sub) {
      const int k = s * 2 + sub;                   // 64-col chunk index 0..7
      if (k * 64 > wave * 32 + 287) continue;      // causal: no col in chunk reachable
      {                                            // cell-interval skip (exact)
        int clo = cj[k * 64], chi = cj[k * 64 + 63];
        if (chi < crw_lo || clo > crw_hi) continue;
      }
      const int gj0 = w0 - 256 + k * 64;           // global col base of chunk
      const int lr0 = sub * 64;                    // local row base in Kc stage
      const bool prevhalf = (k < 4);

#pragma unroll
      for (int mi = 0; mi < 2; ++mi) {
        f32x4 sc[4] = {};
        __builtin_amdgcn_s_setprio(1);
#pragma unroll
        for (int ks = 0; ks < 2; ++ks) {
          int cb = (ks * 32 + g * 8) * 2;
          bf16x8 aq = prevhalf ? qfB[mi][ks] : qf[mi][ks];
#pragma unroll
          for (int ni = 0; ni < 4; ++ni) {
            int r = lr0 + ni * 16 + ln15;
            bf16x8 kf = *(const bf16x8*)((const char*)Kc[cur] + r * 128 + (cb ^ ((r & 7) << 4)));
            sc[ni] = MFMA16(aq, kf, sc[ni]);
          }
        }
        __builtin_amdgcn_s_setprio(0);
        // mask + row max (scores pre-scaled via Q)
        float mx[4] = {NEGF, NEGF, NEGF, NEGF};
#pragma unroll
        for (int ni = 0; ni < 4; ++ni)
#pragma unroll
          for (int r = 0; r < 4; ++r) {
            int iloc = wave * 32 + mi * 16 + g * 4 + r;
            int p = k * 64 + ni * 16 + ln15;
            bool ok = (p <= iloc + 256) && (ci[iloc] == cj[p]);
            float sv = ok ? sc[ni][r] : NEGF;
            sc[ni][r] = sv;
            mx[r] = fmaxf(mx[r], sv);
          }
#pragma unroll
        for (int d = 1; d < 16; d <<= 1)
#pragma unroll
          for (int r = 0; r < 4; ++r) mx[r] = fmaxf(mx[r], __shfl_xor(mx[r], d));
        float rs[4] = {0.f, 0.f, 0.f, 0.f};
        // T13 defer-max: rescale only if max grew by > 8
        bool big = false;
#pragma unroll
        for (int r = 0; r < 4; ++r) big = big || (mx[r] > mrow[mi][r] + 8.0f);
        if (__any(big)) {
#pragma unroll
          for (int r = 0; r < 4; ++r) {
            float mold = mrow[mi][r];
            float mnew = fmaxf(mold, mx[r]);
            float alpha = __expf(mold - mnew);  // NEG,NEG -> 1; NEG,finite -> 0
            mrow[mi][r] = mnew;
            lrow[mi][r] *= alpha;
#pragma unroll
            for (int nd = 0; nd < 4; ++nd) Oa[mi][nd][r] *= alpha;
          }
        }
#pragma unroll
        for (int ni = 0; ni < 4; ++ni)
#pragma unroll
          for (int r = 0; r < 4; ++r) {
            float sv = sc[ni][r];
            float p = (sv > NEGF * 0.5f) ? __expf(sv - mrow[mi][r]) : 0.f;
            rs[r] += p;
            int row = mi * 16 + g * 4 + r;
            int colb = (ni * 16 + ln15) * 2;
            *(u16*)((char*)Pl + wave * 4096 + row * 128 + (colb ^ ((row & 7) << 4))) = f2b(p);
          }
#pragma unroll
        for (int d = 1; d < 16; d <<= 1)
#pragma unroll
          for (int r = 0; r < 4; ++r) rs[r] += __shfl_xor(rs[r], d);
#pragma unroll
        for (int r = 0; r < 4; ++r) lrow[mi][r] += rs[r];
      }  // mi

      // PV: O += P(32x64) * V(64x64); V fragments direct from global
#pragma unroll
      for (int jb = 0; jb < 2; ++jb) {
        bf16x8 pa[2], vb[4];
        int cb = (jb * 32 + g * 8) * 2;
#pragma unroll
        for (int mi = 0; mi < 2; ++mi) {
          int row = mi * 16 + ln15;
          pa[mi] = *(const bf16x8*)((const char*)Pl + wave * 4096 + row * 128 + (cb ^ ((row & 7) << 4)));
        }
#pragma unroll
        for (int nd = 0; nd < 4; ++nd) {
          int d = nd * 16 + ln15;
          int p0 = gj0 + jb * 32 + g * 8;
          vb[nd] = *(const bf16x8*)(vT + base + (size_t)d * LSEQ + p0);
        }
        __builtin_amdgcn_s_setprio(1);
#pragma unroll
        for (int mi = 0; mi < 2; ++mi)
#pragma unroll
          for (int nd = 0; nd < 4; ++nd) Oa[mi][nd] = MFMA16(pa[mi], vb[nd], Oa[mi][nd]);
        __builtin_amdgcn_s_setprio(0);
      }
    }  // sub

    __syncthreads();  // stage s+1 writes complete + all readers of Kc[cur] done
  }  // stages

  // epilogue: normalize and store
#pragma unroll
  for (int mi = 0; mi < 2; ++mi)
#pragma unroll
    for (int r = 0; r < 4; ++r) {
      float invl = 1.0f / lrow[mi][r];
      int gi = w0 + wave * 32 + mi * 16 + g * 4 + r;
      size_t ob = ((size_t)b * LSEQ + gi) * DM + h * HD;
#pragma unroll
      for (int nd = 0; nd < 4; ++nd) o[ob + nd * 16 + ln15] = f2b(Oa[mi][nd][r] * invl);
    }
#undef STAGE_K
}

extern "C" void kernel_launch(void* const* d_in, const int* in_sizes, int n_in,
                              void* d_out, int out_size, void* d_ws, size_t ws_size,
                              hipStream_t stream) {
  const float* q = (const float*)d_in[0];
  const float* k = (const float*)d_in[1];
  const float* v = (const float*)d_in[2];
  const int* cell = (const int*)d_in[3];
  const float* lnw[4] = {(const float*)d_in[4], (const float*)d_in[8], (const float*)d_in[12], (const float*)d_in[16]};
  const float* lnb[4] = {(const float*)d_in[5], (const float*)d_in[9], (const float*)d_in[13], (const float*)d_in[17]};
  const float* Wm[4]  = {(const float*)d_in[6], (const float*)d_in[10], (const float*)d_in[14], (const float*)d_in[18]};
  const float* bi[4]  = {(const float*)d_in[7], (const float*)d_in[11], (const float*)d_in[15], (const float*)d_in[19]};

  char* ws = (char*)d_ws;
  u16* xlnq  = (u16*)(ws);               // 16 MiB: LN'd q (also reused for LN(o))
  u16* wbf   = (u16*)(ws + 16777216);    // 8 MiB: 4 bf16 weights
  u16* qrot  = (u16*)(ws + 25165824);    // 16 MiB
  u16* krot  = (u16*)(ws + 41943040);    // 16 MiB (single K view; old krB slot unused)
  u16* vT    = (u16*)(ws + 75497472);    // 16 MiB
  u16* obuf  = (u16*)(ws + 92274688);    // 16 MiB: xln_k, then attn output
  float* ropc = (float*)(ws + 109051904);
  float* rops = (float*)(ws + 109182976);  // end ~104.3 MiB
  u16* xlnk = obuf;                      // alias: free until attn writes
  u16* xlnv = (u16*)d_out;               // scratch in d_out (fully overwritten by gemm_o)

  cvtw<<<1024, 256, 0, stream>>>((const float4*)Wm[0], (const float4*)Wm[1],
                                 (const float4*)Wm[2], (const float4*)Wm[3], (ushort4*)wbf);
  rope_build<<<512, 64, 0, stream>>>(ropc, rops);

  dim3 lng(8192, 3);
  ln_qkv<<<lng, 256, 0, stream>>>((const float4*)q, (const float4*)k, (const float4*)v,
                                  lnw[0], lnb[0], lnw[1], lnb[1], lnw[2], lnb[2],
                                  (ushort4*)xlnq, (ushort4*)xlnk, (ushort4*)xlnv);
  dim3 gq(512, 3);
  gemm_qkv<<<gq, 256, 0, stream>>>(xlnq, xlnk, xlnv, wbf, bi[0], bi[1], bi[2],
                                   ropc, rops, qrot, krot, vT);
  attn_kernel<<<512, 512, 0, stream>>>(qrot, krot, vT, cell, ropc, rops, obuf);
  ln_rows<<<8192, 256, 0, stream>>>((const ushort4*)obuf, lnw[3], lnb[3], (ushort4*)xlnq);
  gemm_o<<<512, 256, 0, stream>>>(xlnq, wbf + 3145728, bi[3], (float*)d_out);
}